// Round 1
// baseline (4632.265 us; speedup 1.0000x reference)
//
#include <hip/hip_runtime.h>
#include <hip/hip_bf16.h>
#include <math.h>

#define NNODES 50000
#define NEDGES 800000
#define HID 256

// ---------------- workspace layout (bytes, all 1024-aligned) ----------------
#define OFF_COUNTS   0ull                      // int[50000]
#define OFF_CURSOR   200704ull                 // int[50000]
#define OFF_WIN      401408ull                 // float[50000]
#define OFF_STATS    602112ull                 // float[13*512]  per-layer col sums/sumsq
#define OFF_S        628736ull                 // float[1024]    edge-mlp stats
#define ZERO_END     632832ull
#define OFF_ST       632832ull                 // float[512]     current bn affine (s,t)
#define OFF_AB       634880ull                 // float[1024]    mlp affine a1,b1,a2,b2
#define OFF_OFFSETS  638976ull                 // int[50001]
#define OFF_SROW     840704ull                 // int[800000]
#define OFF_SEW      4040704ull                // float[800000]
#define OFF_TMP16    7240704ull                // float[50000*16]
#define OFF_HRAW     10440704ull               // float[50000*16]
#define OFF_BUFP     13640704ull               // float[50000*256]
#define OFF_BUFQ     64840704ull               // float[50000*256]
// uv aliases BUFP..BUFQ region: float[50000*512] = 102.4 MB exactly

// ---------------- preprocessing ----------------

__global__ void hist_kernel(const int* __restrict__ ei, const float* __restrict__ ew,
                            int* __restrict__ counts, float* __restrict__ w_in, int E) {
    for (int i = blockIdx.x * blockDim.x + threadIdx.x; i < E; i += gridDim.x * blockDim.x) {
        int c = ei[E + i];
        atomicAdd(&counts[c], 1);
        atomicAdd(&w_in[c], ew[i]);
    }
}

__global__ void scan_kernel(const int* __restrict__ counts, int* __restrict__ offsets, int N) {
    __shared__ int buf[1024];
    __shared__ int carry_s;
    int tid = threadIdx.x;
    if (tid == 0) carry_s = 0;
    __syncthreads();
    for (int base = 0; base < N; base += 1024) {
        int v = (base + tid < N) ? counts[base + tid] : 0;
        buf[tid] = v;
        __syncthreads();
        for (int off = 1; off < 1024; off <<= 1) {
            int add = (tid >= off) ? buf[tid - off] : 0;
            __syncthreads();
            buf[tid] += add;
            __syncthreads();
        }
        int incl = buf[tid];
        if (base + tid < N) offsets[base + tid] = carry_s + incl - v;
        __syncthreads();
        if (tid == 1023) carry_s += buf[1023];
        __syncthreads();
    }
    if (tid == 0) offsets[N] = carry_s;
}

__global__ void scatter_kernel(const int* __restrict__ ei, const float* __restrict__ ew,
                               const int* __restrict__ offsets, int* __restrict__ cursor,
                               int* __restrict__ srow, float* __restrict__ sew, int E) {
    for (int i = blockIdx.x * blockDim.x + threadIdx.x; i < E; i += gridDim.x * blockDim.x) {
        int c = ei[E + i];
        int p = offsets[c] + atomicAdd(&cursor[c], 1);
        srow[p] = ei[i];
        sew[p] = ew[i];
    }
}

// ---------------- BN column stats ----------------

__global__ __launch_bounds__(256) void colstats256(const float* __restrict__ h,
                                                   float* __restrict__ sums, int M) {
    int c = threadIdx.x;
    float s = 0.f, q = 0.f;
    for (int r = blockIdx.x; r < M; r += gridDim.x) {
        float v = h[r * 256 + c];
        s += v; q += v * v;
    }
    atomicAdd(&sums[c], s);
    atomicAdd(&sums[256 + c], q);
}

__global__ __launch_bounds__(256) void colstats_small(const float* __restrict__ h,
                                                      float* __restrict__ sums, int C, int M) {
    int c = threadIdx.x % C;
    int rpb = blockDim.x / C;
    int rl = threadIdx.x / C;
    float s = 0.f, q = 0.f;
    for (int r = blockIdx.x * rpb + rl; r < M; r += gridDim.x * rpb) {
        float v = h[r * C + c];
        s += v; q += v * v;
    }
    atomicAdd(&sums[c], s);
    atomicAdd(&sums[C + c], q);
}

__global__ void bn_finalize(const float* __restrict__ sums, const float* __restrict__ g,
                            const float* __restrict__ b, float* __restrict__ st, int C, int M) {
    int c = threadIdx.x;
    if (c >= C) return;
    float mean = sums[c] / (float)M;
    float var  = sums[C + c] / (float)M - mean * mean;
    float sc = g[c] * rsqrtf(var + 1e-5f);
    st[c] = sc;
    st[C + c] = b[c] - mean * sc;
}

// ---------------- SpMM (CSR by destination) ----------------

__global__ __launch_bounds__(256) void spmm256(const float* __restrict__ T,
                                               const int* __restrict__ srow,
                                               const float* __restrict__ sew,
                                               const int* __restrict__ off,
                                               float* __restrict__ out, int relu) {
    int n = blockIdx.x;
    int c = threadIdx.x;
    int e0 = off[n], e1 = off[n + 1];
    float acc = 0.f;
    int e = e0;
    for (; e + 3 < e1; e += 4) {
        int r0 = srow[e], r1 = srow[e + 1], r2 = srow[e + 2], r3 = srow[e + 3];
        float w0 = sew[e], w1 = sew[e + 1], w2 = sew[e + 2], w3 = sew[e + 3];
        float t0 = T[r0 * 256 + c], t1 = T[r1 * 256 + c];
        float t2 = T[r2 * 256 + c], t3 = T[r3 * 256 + c];
        acc += w0 * t0 + w1 * t1 + w2 * t2 + w3 * t3;
    }
    for (; e < e1; ++e) acc += sew[e] * T[srow[e] * 256 + c];
    if (relu) acc = fmaxf(acc, 0.f);
    out[n * 256 + c] = acc;
}

__global__ __launch_bounds__(256) void spmm_small(const float* __restrict__ T,
                                                  const int* __restrict__ srow,
                                                  const float* __restrict__ sew,
                                                  const int* __restrict__ off,
                                                  float* __restrict__ out,
                                                  int C, int N, int relu) {
    int npb = blockDim.x / C;
    int local = threadIdx.x / C;
    int c = threadIdx.x % C;
    int n = blockIdx.x * npb + local;
    if (n >= N) return;
    int e0 = off[n], e1 = off[n + 1];
    float acc = 0.f;
    for (int e = e0; e < e1; ++e) acc += sew[e] * T[srow[e] * C + c];
    if (relu) acc = fmaxf(acc, 0.f);
    out[n * C + c] = acc;
}

// ---------------- layer 0 finalize: h = relu((agg2*s + w_in*t)@W0 + w_in*b0) ----------------

__global__ __launch_bounds__(256) void layer0_fin(const float* __restrict__ agg2,
                                                  const float* __restrict__ w_in,
                                                  const float* __restrict__ st,
                                                  const float* __restrict__ W0,
                                                  const float* __restrict__ b0,
                                                  float* __restrict__ h, int N) {
    int n = blockIdx.x;
    int j = threadIdx.x;
    float wi = w_in[n];
    float a0 = agg2[n * 2 + 0] * st[0] + wi * st[2];
    float a1 = agg2[n * 2 + 1] * st[1] + wi * st[3];
    float v = a0 * W0[j] + a1 * W0[256 + j] + wi * b0[j];
    h[n * 256 + j] = fmaxf(v, 0.f);
}

// ---------------- fp32 GEMM: out = (H*s+t) @ W + bias;  [M,256]x[256,256] ----------------

__global__ __launch_bounds__(256) void gemm_aff(const float* __restrict__ H,
                                                const float* __restrict__ W,
                                                const float* __restrict__ bias,
                                                const float* __restrict__ st,
                                                float* __restrict__ out, int M) {
    __shared__ float As[16][65];
    __shared__ float Bs[16][256];
    int tid = threadIdx.x;
    int m0 = blockIdx.x << 6;
    int tr = tid >> 5;       // 0..7
    int tc = tid & 31;       // 0..31
    float acc[8][8];
#pragma unroll
    for (int i = 0; i < 8; i++)
#pragma unroll
        for (int j = 0; j < 8; j++) acc[i][j] = 0.f;

    int arow = tid >> 2;             // 0..63
    int ak = (tid & 3) << 2;         // 0,4,8,12
    int grow = m0 + arow; if (grow >= M) grow = M - 1;
    const float* hptr = H + grow * 256 + ak;
    int bk = tid >> 4;               // 0..15
    int bc = (tid & 15) << 4;        // 0..240

    for (int k0 = 0; k0 < 256; k0 += 16) {
        float4 a4 = *(const float4*)(hptr + k0);
        float4 s4 = *(const float4*)(st + k0 + ak);
        float4 t4 = *(const float4*)(st + 256 + k0 + ak);
        As[ak + 0][arow] = a4.x * s4.x + t4.x;
        As[ak + 1][arow] = a4.y * s4.y + t4.y;
        As[ak + 2][arow] = a4.z * s4.z + t4.z;
        As[ak + 3][arow] = a4.w * s4.w + t4.w;
        const float* wp = W + (k0 + bk) * 256 + bc;
        float4 b0v = *(const float4*)(wp + 0);
        float4 b1v = *(const float4*)(wp + 4);
        float4 b2v = *(const float4*)(wp + 8);
        float4 b3v = *(const float4*)(wp + 12);
        *(float4*)&Bs[bk][bc + 0]  = b0v;
        *(float4*)&Bs[bk][bc + 4]  = b1v;
        *(float4*)&Bs[bk][bc + 8]  = b2v;
        *(float4*)&Bs[bk][bc + 12] = b3v;
        __syncthreads();
#pragma unroll
        for (int k = 0; k < 16; k++) {
            float a[8];
#pragma unroll
            for (int i = 0; i < 8; i++) a[i] = As[k][tr + (i << 3)];
#pragma unroll
            for (int j = 0; j < 4; j++) {
                float2 b2 = *(const float2*)&Bs[k][(tc << 1) + (j << 6)];
#pragma unroll
                for (int i = 0; i < 8; i++) {
                    acc[i][2 * j]     += a[i] * b2.x;
                    acc[i][2 * j + 1] += a[i] * b2.y;
                }
            }
        }
        __syncthreads();
    }
#pragma unroll
    for (int i = 0; i < 8; i++) {
        int r = m0 + tr + (i << 3);
        if (r < M) {
#pragma unroll
            for (int j = 0; j < 4; j++) {
                int c = (tc << 1) + (j << 6);
                float2 o;
                o.x = acc[i][2 * j]     + bias[c];
                o.y = acc[i][2 * j + 1] + bias[c + 1];
                *(float2*)(out + r * 256 + c) = o;
            }
        }
    }
}

// ---------------- last GCN linear: [M,256] x [256,16] ----------------

__global__ __launch_bounds__(256) void gemm16(const float* __restrict__ H,
                                              const float* __restrict__ Wl,
                                              const float* __restrict__ bl,
                                              const float* __restrict__ st,
                                              float* __restrict__ out, int M) {
    __shared__ float Hs[16][256];
    __shared__ float Ws[256][16];
    int tid = threadIdx.x;
    int n0 = blockIdx.x << 4;
    for (int i = tid; i < 4096; i += 256) Ws[i >> 4][i & 15] = Wl[i];
    for (int i = tid; i < 4096; i += 256) {
        int r = i >> 8, k = i & 255;
        int n = n0 + r;
        Hs[r][k] = (n < M) ? (H[n * 256 + k] * st[k] + st[256 + k]) : 0.f;
    }
    __syncthreads();
    int r = tid >> 4, j = tid & 15;
    float acc = bl[j];
    for (int k = 0; k < 256; k++) acc += Hs[r][k] * Ws[k][j];
    if (n0 + r < M) out[(n0 + r) * 16 + j] = acc;
}

// ---------------- u/v precompute: u = bn(hraw)@mW1[0:16], v = bn(hraw)@mW1[16:32] ----------------

__global__ __launch_bounds__(256) void uv_kernel(const float* __restrict__ hraw,
                                                 const float* __restrict__ st,
                                                 const float* __restrict__ mW1,
                                                 float* __restrict__ uv, int N) {
    __shared__ float Ws[32][256];
    __shared__ float Hs[8][16];
    int tid = threadIdx.x;
    for (int i = tid; i < 32 * 256; i += 256) Ws[i >> 8][i & 255] = mW1[i];
    int n0 = blockIdx.x << 3;
    for (int i = tid; i < 8 * 16; i += 256) {
        int r = i >> 4, k = i & 15;
        int n = n0 + r;
        Hs[r][k] = (n < N) ? (hraw[n * 16 + k] * st[k] + st[16 + k]) : 0.f;
    }
    __syncthreads();
    int j = tid;
#pragma unroll
    for (int r = 0; r < 8; r++) {
        int n = n0 + r;
        if (n >= N) break;
        float u = 0.f, v = 0.f;
#pragma unroll
        for (int k = 0; k < 16; k++) {
            float hval = Hs[r][k];
            u += hval * Ws[k][j];
            v += hval * Ws[16 + k][j];
        }
        uv[n * 512 + j] = u;
        uv[n * 512 + 256 + j] = v;
    }
}

// ---------------- edge MLP stats: sums/sumsq of w1 = u[r]+v[c], w2 = v[r]+u[c] ----------------

__global__ __launch_bounds__(256) void edge_stats(const float* __restrict__ uv,
                                                  const int* __restrict__ row,
                                                  const int* __restrict__ col,
                                                  float* __restrict__ S, int E) {
    __shared__ float red[4][1024];
    int tid = threadIdx.x;
    int w = tid >> 6, l = tid & 63;
    float s1[4] = {0, 0, 0, 0}, q1[4] = {0, 0, 0, 0};
    float s2[4] = {0, 0, 0, 0}, q2[4] = {0, 0, 0, 0};
    int gw = blockIdx.x * 4 + w;
    int nw = gridDim.x * 4;
    for (int e = gw; e < E; e += nw) {
        int r = row[e], c = col[e];
        float4 ur = *(const float4*)(uv + r * 512 + l * 4);
        float4 vr = *(const float4*)(uv + r * 512 + 256 + l * 4);
        float4 uc = *(const float4*)(uv + c * 512 + l * 4);
        float4 vc = *(const float4*)(uv + c * 512 + 256 + l * 4);
        float w1x = ur.x + vc.x, w1y = ur.y + vc.y, w1z = ur.z + vc.z, w1w = ur.w + vc.w;
        float w2x = vr.x + uc.x, w2y = vr.y + uc.y, w2z = vr.z + uc.z, w2w = vr.w + uc.w;
        s1[0] += w1x; s1[1] += w1y; s1[2] += w1z; s1[3] += w1w;
        q1[0] += w1x * w1x; q1[1] += w1y * w1y; q1[2] += w1z * w1z; q1[3] += w1w * w1w;
        s2[0] += w2x; s2[1] += w2y; s2[2] += w2z; s2[3] += w2w;
        q2[0] += w2x * w2x; q2[1] += w2y * w2y; q2[2] += w2z * w2z; q2[3] += w2w * w2w;
    }
#pragma unroll
    for (int j = 0; j < 4; j++) {
        red[w][0 * 256 + 4 * l + j] = s1[j];
        red[w][1 * 256 + 4 * l + j] = q1[j];
        red[w][2 * 256 + 4 * l + j] = s2[j];
        red[w][3 * 256 + 4 * l + j] = q2[j];
    }
    __syncthreads();
    for (int i = tid; i < 1024; i += 256) {
        float v = red[0][i] + red[1][i] + red[2][i] + red[3][i];
        atomicAdd(&S[i], v);
    }
}

__global__ void mlp_finalize(const float* __restrict__ S, const float* __restrict__ g,
                             const float* __restrict__ b, float* __restrict__ ab, int E) {
    int c = threadIdx.x;
    float inv = 1.f / (float)E;
    float m1 = S[c] * inv;
    float v1 = S[256 + c] * inv - m1 * m1;
    float m2 = S[512 + c] * inv;
    float v2 = S[768 + c] * inv - m2 * m2;
    float a1 = g[c] * rsqrtf(v1 + 1e-5f);
    float a2 = g[c] * rsqrtf(v2 + 1e-5f);
    ab[c] = a1;
    ab[256 + c] = b[c] - m1 * a1;
    ab[512 + c] = a2;
    ab[768 + c] = b[c] - m2 * a2;
}

// ---------------- edge MLP output ----------------

__global__ __launch_bounds__(256) void edge_out(const float* __restrict__ uv,
                                                const int* __restrict__ row,
                                                const int* __restrict__ col,
                                                const float* __restrict__ ab,
                                                const float* __restrict__ mW2,
                                                const float* __restrict__ mb2,
                                                float* __restrict__ out, int E) {
    int tid = threadIdx.x;
    int w = tid >> 6, l = tid & 63;
    float4 A1 = *(const float4*)(ab + 4 * l);
    float4 B1 = *(const float4*)(ab + 256 + 4 * l);
    float4 A2 = *(const float4*)(ab + 512 + 4 * l);
    float4 B2 = *(const float4*)(ab + 768 + 4 * l);
    float4 W2 = *(const float4*)(mW2 + 4 * l);
    float mb2v = mb2[0];
    int gw = blockIdx.x * 4 + w;
    int nw = gridDim.x * 4;
    for (int e = gw; e < E; e += nw) {
        int r = row[e], c = col[e];
        float4 ur = *(const float4*)(uv + r * 512 + l * 4);
        float4 vr = *(const float4*)(uv + r * 512 + 256 + l * 4);
        float4 uc = *(const float4*)(uv + c * 512 + l * 4);
        float4 vc = *(const float4*)(uv + c * 512 + 256 + l * 4);
        float p = 0.f;
        p += fmaxf((ur.x + vc.x) * A1.x + B1.x, 0.f) * W2.x;
        p += fmaxf((ur.y + vc.y) * A1.y + B1.y, 0.f) * W2.y;
        p += fmaxf((ur.z + vc.z) * A1.z + B1.z, 0.f) * W2.z;
        p += fmaxf((ur.w + vc.w) * A1.w + B1.w, 0.f) * W2.w;
        p += fmaxf((vr.x + uc.x) * A2.x + B2.x, 0.f) * W2.x;
        p += fmaxf((vr.y + uc.y) * A2.y + B2.y, 0.f) * W2.y;
        p += fmaxf((vr.z + uc.z) * A2.z + B2.z, 0.f) * W2.z;
        p += fmaxf((vr.w + uc.w) * A2.w + B2.w, 0.f) * W2.w;
#pragma unroll
        for (int off = 32; off > 0; off >>= 1) p += __shfl_down(p, off);
        if (l == 0) out[e] = 1.f / (1.f + expf(-(0.5f * p + mb2v)));
    }
}

// ---------------- launch ----------------

extern "C" void kernel_launch(void* const* d_in, const int* in_sizes, int n_in,
                              void* d_out, int out_size, void* d_ws, size_t ws_size,
                              hipStream_t stream) {
    const float* x     = (const float*)d_in[0];
    const int*   ei    = (const int*)d_in[1];
    const float* ew    = (const float*)d_in[2];
    const float* W0    = (const float*)d_in[3];
    const float* b0    = (const float*)d_in[4];
    const float* Wm    = (const float*)d_in[5];
    const float* bm    = (const float*)d_in[6];
    const float* Wl    = (const float*)d_in[7];
    const float* bl    = (const float*)d_in[8];
    const float* bn0_g = (const float*)d_in[9];
    const float* bn0_b = (const float*)d_in[10];
    const float* bnm_g = (const float*)d_in[11];
    const float* bnm_b = (const float*)d_in[12];
    const float* bno_g = (const float*)d_in[13];
    const float* bno_b = (const float*)d_in[14];
    const float* mW1   = (const float*)d_in[15];
    // d_in[16] = mb1: cancels inside training-mode BN, unused
    const float* mbn_g = (const float*)d_in[17];
    const float* mbn_b = (const float*)d_in[18];
    const float* mW2   = (const float*)d_in[19];
    const float* mb2   = (const float*)d_in[20];
    float* outp = (float*)d_out;

    char* ws = (char*)d_ws;
    int*   counts  = (int*)(ws + OFF_COUNTS);
    int*   cursor  = (int*)(ws + OFF_CURSOR);
    float* w_in    = (float*)(ws + OFF_WIN);
    float* stats   = (float*)(ws + OFF_STATS);
    float* S       = (float*)(ws + OFF_S);
    float* st      = (float*)(ws + OFF_ST);
    float* ab      = (float*)(ws + OFF_AB);
    int*   offsets = (int*)(ws + OFF_OFFSETS);
    int*   srow    = (int*)(ws + OFF_SROW);
    float* sew     = (float*)(ws + OFF_SEW);
    float* tmp16   = (float*)(ws + OFF_TMP16);
    float* hraw    = (float*)(ws + OFF_HRAW);
    float* bufP    = (float*)(ws + OFF_BUFP);
    float* bufQ    = (float*)(ws + OFF_BUFQ);
    float* agg2    = tmp16;            // reuse (layer0 aggregate, 2 cols)
    float* uv      = bufP;             // aliases BUFP+BUFQ (102.4 MB) after GCN stack

    const int N = NNODES, E = NEDGES;

    // zero the atomically-accumulated regions (counts, cursor, w_in, stats, S)
    hipMemsetAsync(ws, 0, ZERO_END, stream);

    // CSR by destination
    hist_kernel<<<1024, 256, 0, stream>>>(ei, ew, counts, w_in, E);
    scan_kernel<<<1, 1024, 0, stream>>>(counts, offsets, N);
    scatter_kernel<<<1024, 256, 0, stream>>>(ei, ew, offsets, cursor, srow, sew, E);

    // ---- layer 0: aggregate raw 2-col input first, then fold BN+linear ----
    colstats_small<<<128, 256, 0, stream>>>(x, stats + 0 * 512, 2, N);
    bn_finalize<<<1, 256, 0, stream>>>(stats + 0 * 512, bn0_g, bn0_b, st, 2, N);
    spmm_small<<<(N + 127) / 128, 256, 0, stream>>>(x, srow, sew, offsets, agg2, 2, N, 0);
    layer0_fin<<<N, 256, 0, stream>>>(agg2, w_in, st, W0, b0, bufP, N);

    // ---- 10 mid layers ----
    for (int i = 0; i < 10; i++) {
        colstats256<<<512, 256, 0, stream>>>(bufP, stats + (1 + i) * 512, N);
        bn_finalize<<<1, 256, 0, stream>>>(stats + (1 + i) * 512, bnm_g + i * 256,
                                           bnm_b + i * 256, st, 256, N);
        gemm_aff<<<(N + 63) / 64, 256, 0, stream>>>(bufP, Wm + i * 65536, bm + i * 256,
                                                    st, bufQ, N);
        spmm256<<<N, 256, 0, stream>>>(bufQ, srow, sew, offsets, bufP, 1);
    }

    // ---- last GCN layer (256 -> 16) ----
    colstats256<<<512, 256, 0, stream>>>(bufP, stats + 11 * 512, N);
    bn_finalize<<<1, 256, 0, stream>>>(stats + 11 * 512, bnm_g + 10 * 256,
                                       bnm_b + 10 * 256, st, 256, N);
    gemm16<<<(N + 15) / 16, 256, 0, stream>>>(bufP, Wl, bl, st, tmp16, N);
    spmm_small<<<(N + 15) / 16, 256, 0, stream>>>(tmp16, srow, sew, offsets, hraw, 16, N, 1);

    // ---- final BN + u/v precompute ----
    colstats_small<<<512, 256, 0, stream>>>(hraw, stats + 12 * 512, 16, N);
    bn_finalize<<<1, 256, 0, stream>>>(stats + 12 * 512, bno_g, bno_b, st, 16, N);
    uv_kernel<<<(N + 7) / 8, 256, 0, stream>>>(hraw, st, mW1, uv, N);

    // ---- edge MLP: stats pass, finalize, output pass ----
    edge_stats<<<1024, 256, 0, stream>>>(uv, ei, ei + E, S, E);
    mlp_finalize<<<1, 256, 0, stream>>>(S, mbn_g, mbn_b, ab, E);
    edge_out<<<1024, 256, 0, stream>>>(uv, ei, ei + E, ab, mW2, mb2, outp, E);
}

// Round 2
// 3041.023 us; speedup vs baseline: 1.5233x; 1.5233x over previous
//
#include <hip/hip_runtime.h>
#include <hip/hip_bf16.h>
#include <hip/hip_fp16.h>
#include <math.h>

#define NNODES 50000
#define NEDGES 800000

// ---------------- workspace layout (bytes) ----------------
#define OFF_COUNTS   0ull                      // int[50000]
#define OFF_CURSOR   200704ull                 // int[50000]
#define OFF_WIN      401408ull                 // float[50000]
#define OFF_STATS    602112ull                 // float[13*512]
#define OFF_S        628736ull                 // float[1024]
#define ZERO_END     632832ull
#define OFF_ST       632832ull                 // float[512]
#define OFF_AB       634880ull                 // float[1024]
#define OFF_OFFSETS  638976ull                 // int[50001]
#define OFF_SROW     840704ull                 // int[800000]
#define OFF_SEW      4040704ull                // float[800000]
#define OFF_TMP16    7240704ull                // float[50000*16]
#define OFF_HRAW     10440704ull               // float[50000*16]
#define OFF_WTHI     13640704ull               // ushort[10*256*256] bf16 hi (transposed)
#define OFF_WTLO     14951424ull               // ushort[10*256*256] bf16 lo
#define OFF_BUFQ     16262144ull               // half[50000*256]
#define OFF_BUFP     41862144ull               // float[50000*256]; uv (half[50000*512]) aliases

typedef __attribute__((ext_vector_type(8))) short bf16x8;
typedef __attribute__((ext_vector_type(4))) float f32x4;

union H4 { ushort4 u; __half h[4]; };

static __device__ inline ushort f2bf_rne(float f) {
    __hip_bfloat16 b = __float2bfloat16(f);
    union { __hip_bfloat16 bb; ushort u; } cv; cv.bb = b; return cv.u;
}

// split f into bf16 hi (truncate) + bf16 lo (RNE of remainder)
static __device__ inline void bf_split(float f, ushort& hi, ushort& lo) {
    unsigned u = __float_as_uint(f);
    hi = (ushort)(u >> 16);
    float rem = f - __uint_as_float(u & 0xffff0000u);
    lo = f2bf_rne(rem);
}

// ---------------- preprocessing ----------------

__global__ void hist_kernel(const int* __restrict__ ei, const float* __restrict__ ew,
                            int* __restrict__ counts, float* __restrict__ w_in, int E) {
    for (int i = blockIdx.x * blockDim.x + threadIdx.x; i < E; i += gridDim.x * blockDim.x) {
        int c = ei[E + i];
        atomicAdd(&counts[c], 1);
        atomicAdd(&w_in[c], ew[i]);
    }
}

__global__ void scan_kernel(const int* __restrict__ counts, int* __restrict__ offsets, int N) {
    __shared__ int wsum[16];
    __shared__ int carry_s;
    int tid = threadIdx.x;
    int lane = tid & 63, w = tid >> 6;
    if (tid == 0) carry_s = 0;
    __syncthreads();
    for (int base = 0; base < N; base += 1024) {
        int v = (base + tid < N) ? counts[base + tid] : 0;
        int x = v;
#pragma unroll
        for (int off = 1; off < 64; off <<= 1) {
            int y = __shfl_up(x, off);
            if (lane >= off) x += y;
        }
        if (lane == 63) wsum[w] = x;
        __syncthreads();
        if (w == 0 && lane < 16) {
            int s = wsum[lane];
#pragma unroll
            for (int off = 1; off < 16; off <<= 1) {
                int y = __shfl_up(s, off);
                if (lane >= off) s += y;
            }
            wsum[lane] = s;
        }
        __syncthreads();
        int wbase = (w > 0) ? wsum[w - 1] : 0;
        int incl = carry_s + wbase + x;
        if (base + tid < N) offsets[base + tid] = incl - v;
        __syncthreads();
        if (tid == 0) carry_s += wsum[15];
        __syncthreads();
    }
    if (tid == 0) offsets[N] = carry_s;
}

__global__ void scatter_kernel(const int* __restrict__ ei, const float* __restrict__ ew,
                               const int* __restrict__ offsets, int* __restrict__ cursor,
                               int* __restrict__ srow, float* __restrict__ sew, int E) {
    for (int i = blockIdx.x * blockDim.x + threadIdx.x; i < E; i += gridDim.x * blockDim.x) {
        int c = ei[E + i];
        int p = offsets[c] + atomicAdd(&cursor[c], 1);
        srow[p] = ei[i];
        sew[p] = ew[i];
    }
}

// ---------------- weight preconvert: Wt_hi/lo[n][k] = split(Wm[k][n]) ----------------

__global__ __launch_bounds__(256) void wsplit(const float* __restrict__ Wm,
                                              ushort* __restrict__ hi, ushort* __restrict__ lo) {
    __shared__ float tile[32][33];
    int b = blockIdx.x;
    int layer = b >> 6, t = b & 63;
    int tk = (t >> 3) << 5, tn = (t & 7) << 5;
    int tid = threadIdx.x;
    int r = tid >> 5, c = tid & 31;
    const float* W = Wm + layer * 65536;
#pragma unroll
    for (int i = 0; i < 4; i++) tile[r + i * 8][c] = W[(tk + r + i * 8) * 256 + tn + c];
    __syncthreads();
#pragma unroll
    for (int i = 0; i < 4; i++) {
        int n = tn + r + i * 8, k = tk + c;
        float f = tile[c][r + i * 8];
        ushort h, l;
        bf_split(f, h, l);
        hi[layer * 65536 + n * 256 + k] = h;
        lo[layer * 65536 + n * 256 + k] = l;
    }
}

// ---------------- BN column stats ----------------

__global__ __launch_bounds__(256) void colstats256(const float* __restrict__ h,
                                                   float* __restrict__ sums, int M) {
    int c = threadIdx.x;
    float s = 0.f, q = 0.f;
    for (int r = blockIdx.x; r < M; r += gridDim.x) {
        float v = h[r * 256 + c];
        s += v; q += v * v;
    }
    atomicAdd(&sums[c], s);
    atomicAdd(&sums[256 + c], q);
}

__global__ __launch_bounds__(256) void colstats_small(const float* __restrict__ h,
                                                      float* __restrict__ sums, int C, int M) {
    int c = threadIdx.x % C;
    int rpb = blockDim.x / C;
    int rl = threadIdx.x / C;
    float s = 0.f, q = 0.f;
    for (int r = blockIdx.x * rpb + rl; r < M; r += gridDim.x * rpb) {
        float v = h[r * C + c];
        s += v; q += v * v;
    }
    atomicAdd(&sums[c], s);
    atomicAdd(&sums[C + c], q);
}

__global__ void bn_finalize(const float* __restrict__ sums, const float* __restrict__ g,
                            const float* __restrict__ b, float* __restrict__ st, int C, int M) {
    int c = threadIdx.x;
    if (c >= C) return;
    float mean = sums[c] / (float)M;
    float var  = sums[C + c] / (float)M - mean * mean;
    float sc = g[c] * rsqrtf(var + 1e-5f);
    st[c] = sc;
    st[C + c] = b[c] - mean * sc;
}

// ---------------- MFMA GEMM (bf16x3): out_f16 = (H*s+t)@W + bias ----------------
// grid (ceil(M/128), 2); block 256 = 4 waves; wave: 32 rows x 128 cols

__global__ __launch_bounds__(256) void gemm_mfma(const float* __restrict__ H,
                                                 const ushort* __restrict__ Wthi,
                                                 const ushort* __restrict__ Wtlo,
                                                 const float* __restrict__ bias,
                                                 const float* __restrict__ st,
                                                 __half* __restrict__ out, int M) {
    __shared__ __attribute__((aligned(16))) ushort Ahi[128][40];
    __shared__ __attribute__((aligned(16))) ushort Alo[128][40];
    __shared__ __attribute__((aligned(16))) ushort Bhi[128][40];
    __shared__ __attribute__((aligned(16))) ushort Blo[128][40];
    int tid = threadIdx.x;
    int wid = tid >> 6, lane = tid & 63;
    int m0 = blockIdx.x * 128;
    int n0 = blockIdx.y * 128;

    f32x4 acc[2][8];
#pragma unroll
    for (int m = 0; m < 2; m++)
#pragma unroll
        for (int n = 0; n < 8; n++) acc[m][n] = (f32x4){0.f, 0.f, 0.f, 0.f};

    int sr = tid >> 3;               // 0..31 (row within 128 handled per t-step by +32)
    int kq = (tid & 7) << 2;         // 0,4,...,28
    int fr = lane & 15;
    int qo = (lane >> 4) << 3;       // elem offset 0,8,16,24
    int mrow = wid << 5;

    for (int k0 = 0; k0 < 256; k0 += 32) {
        // stage A (affine + split): 128 rows x 32 k
#pragma unroll
        for (int t = 0; t < 4; t++) {
            int r = sr + t * 32;
            int gr = m0 + r; if (gr >= M) gr = M - 1;
            float4 h4 = *(const float4*)(H + gr * 256 + k0 + kq);
            float4 s4 = *(const float4*)(st + k0 + kq);
            float4 t4 = *(const float4*)(st + 256 + k0 + kq);
            float a0 = h4.x * s4.x + t4.x;
            float a1 = h4.y * s4.y + t4.y;
            float a2 = h4.z * s4.z + t4.z;
            float a3 = h4.w * s4.w + t4.w;
            ushort4 vh, vl;
            bf_split(a0, vh.x, vl.x);
            bf_split(a1, vh.y, vl.y);
            bf_split(a2, vh.z, vl.z);
            bf_split(a3, vh.w, vl.w);
            *(ushort4*)&Ahi[r][kq] = vh;
            *(ushort4*)&Alo[r][kq] = vl;
        }
        // stage B: rows n0..n0+127, k chunk
#pragma unroll
        for (int t = 0; t < 4; t++) {
            int n = sr + t * 32;
            ushort4 bh = *(const ushort4*)(Wthi + (n0 + n) * 256 + k0 + kq);
            ushort4 bl = *(const ushort4*)(Wtlo + (n0 + n) * 256 + k0 + kq);
            *(ushort4*)&Bhi[n][kq] = bh;
            *(ushort4*)&Blo[n][kq] = bl;
        }
        __syncthreads();

        bf16x8 ah0 = *(const bf16x8*)&Ahi[mrow + fr][qo];
        bf16x8 ah1 = *(const bf16x8*)&Ahi[mrow + 16 + fr][qo];
        bf16x8 al0 = *(const bf16x8*)&Alo[mrow + fr][qo];
        bf16x8 al1 = *(const bf16x8*)&Alo[mrow + 16 + fr][qo];
#pragma unroll
        for (int nt = 0; nt < 8; nt++) {
            bf16x8 bh = *(const bf16x8*)&Bhi[nt * 16 + fr][qo];
            bf16x8 bl = *(const bf16x8*)&Blo[nt * 16 + fr][qo];
            acc[0][nt] = __builtin_amdgcn_mfma_f32_16x16x32_bf16(ah0, bh, acc[0][nt], 0, 0, 0);
            acc[1][nt] = __builtin_amdgcn_mfma_f32_16x16x32_bf16(ah1, bh, acc[1][nt], 0, 0, 0);
            acc[0][nt] = __builtin_amdgcn_mfma_f32_16x16x32_bf16(al0, bh, acc[0][nt], 0, 0, 0);
            acc[1][nt] = __builtin_amdgcn_mfma_f32_16x16x32_bf16(al1, bh, acc[1][nt], 0, 0, 0);
            acc[0][nt] = __builtin_amdgcn_mfma_f32_16x16x32_bf16(ah0, bl, acc[0][nt], 0, 0, 0);
            acc[1][nt] = __builtin_amdgcn_mfma_f32_16x16x32_bf16(ah1, bl, acc[1][nt], 0, 0, 0);
        }
        __syncthreads();
    }

    // epilogue: C/D layout col=lane&15, row=(lane>>4)*4+j
#pragma unroll
    for (int mt = 0; mt < 2; mt++) {
        int gmb = m0 + mrow + mt * 16 + ((lane >> 4) << 2);
#pragma unroll
        for (int nt = 0; nt < 8; nt++) {
            int gn = n0 + nt * 16 + fr;
            float bv = bias[gn];
#pragma unroll
            for (int j = 0; j < 4; j++) {
                int gm = gmb + j;
                if (gm < M) out[gm * 256 + gn] = __float2half(acc[mt][nt][j] + bv);
            }
        }
    }
}

// ---------------- SpMM fp16 gather (wave per node) ----------------

__global__ __launch_bounds__(256) void spmm_f16(const __half* __restrict__ T,
                                                const int* __restrict__ srow,
                                                const float* __restrict__ sew,
                                                const int* __restrict__ off,
                                                float* __restrict__ outp, int N) {
    int wid = threadIdx.x >> 6, lane = threadIdx.x & 63;
    int n = blockIdx.x * 4 + wid;
    if (n >= N) return;
    int e0 = off[n], e1 = off[n + 1];
    float4 acc = {0.f, 0.f, 0.f, 0.f};
    const ushort* Tu = (const ushort*)T;
    int l4 = lane << 2;
    int e = e0;
    for (; e + 7 < e1; e += 8) {
        int r[8]; float w[8]; H4 v[8];
#pragma unroll
        for (int i = 0; i < 8; i++) { r[i] = srow[e + i]; w[i] = sew[e + i]; }
#pragma unroll
        for (int i = 0; i < 8; i++) v[i].u = *(const ushort4*)(Tu + r[i] * 256 + l4);
#pragma unroll
        for (int i = 0; i < 8; i++) {
            acc.x += w[i] * __half2float(v[i].h[0]);
            acc.y += w[i] * __half2float(v[i].h[1]);
            acc.z += w[i] * __half2float(v[i].h[2]);
            acc.w += w[i] * __half2float(v[i].h[3]);
        }
    }
    for (; e < e1; ++e) {
        int rr = srow[e]; float w = sew[e];
        H4 v; v.u = *(const ushort4*)(Tu + rr * 256 + l4);
        acc.x += w * __half2float(v.h[0]);
        acc.y += w * __half2float(v.h[1]);
        acc.z += w * __half2float(v.h[2]);
        acc.w += w * __half2float(v.h[3]);
    }
    acc.x = fmaxf(acc.x, 0.f); acc.y = fmaxf(acc.y, 0.f);
    acc.z = fmaxf(acc.z, 0.f); acc.w = fmaxf(acc.w, 0.f);
    *(float4*)(outp + n * 256 + l4) = acc;
}

__global__ __launch_bounds__(256) void spmm_small(const float* __restrict__ T,
                                                  const int* __restrict__ srow,
                                                  const float* __restrict__ sew,
                                                  const int* __restrict__ off,
                                                  float* __restrict__ out,
                                                  int C, int N, int relu) {
    int npb = blockDim.x / C;
    int local = threadIdx.x / C;
    int c = threadIdx.x % C;
    int n = blockIdx.x * npb + local;
    if (n >= N) return;
    int e0 = off[n], e1 = off[n + 1];
    float acc = 0.f;
    for (int e = e0; e < e1; ++e) acc += sew[e] * T[srow[e] * C + c];
    if (relu) acc = fmaxf(acc, 0.f);
    out[n * C + c] = acc;
}

// ---------------- layer 0 finalize ----------------

__global__ __launch_bounds__(256) void layer0_fin(const float* __restrict__ agg2,
                                                  const float* __restrict__ w_in,
                                                  const float* __restrict__ st,
                                                  const float* __restrict__ W0,
                                                  const float* __restrict__ b0,
                                                  float* __restrict__ h, int N) {
    int j = threadIdx.x;
    float w0j = W0[j], w1j = W0[256 + j], b0j = b0[j];
    float s0 = st[0], s1 = st[1], t0 = st[2], t1 = st[3];
    int n0 = blockIdx.x << 2;
#pragma unroll
    for (int i = 0; i < 4; i++) {
        int n = n0 + i;
        if (n >= N) break;
        float wi = w_in[n];
        float a0 = agg2[n * 2 + 0] * s0 + wi * t0;
        float a1 = agg2[n * 2 + 1] * s1 + wi * t1;
        float v = a0 * w0j + a1 * w1j + wi * b0j;
        h[n * 256 + j] = fmaxf(v, 0.f);
    }
}

// ---------------- last GCN linear: [M,256] x [256,16] ----------------

__global__ __launch_bounds__(256) void gemm16(const float* __restrict__ H,
                                              const float* __restrict__ Wl,
                                              const float* __restrict__ bl,
                                              const float* __restrict__ st,
                                              float* __restrict__ out, int M) {
    __shared__ float Hs[16][256];
    __shared__ float Ws[256][16];
    int tid = threadIdx.x;
    int n0 = blockIdx.x << 4;
    for (int i = tid; i < 4096; i += 256) Ws[i >> 4][i & 15] = Wl[i];
    for (int i = tid; i < 4096; i += 256) {
        int r = i >> 8, k = i & 255;
        int n = n0 + r;
        Hs[r][k] = (n < M) ? (H[n * 256 + k] * st[k] + st[256 + k]) : 0.f;
    }
    __syncthreads();
    int r = tid >> 4, j = tid & 15;
    float acc = bl[j];
    for (int k = 0; k < 256; k++) acc += Hs[r][k] * Ws[k][j];
    if (n0 + r < M) out[(n0 + r) * 16 + j] = acc;
}

// ---------------- u/v precompute (fp16 out) ----------------

__global__ __launch_bounds__(256) void uv_kernel(const float* __restrict__ hraw,
                                                 const float* __restrict__ st,
                                                 const float* __restrict__ mW1,
                                                 __half* __restrict__ uvh, int N) {
    __shared__ float Ws[32][256];
    __shared__ float Hs[8][16];
    int tid = threadIdx.x;
    for (int i = tid; i < 32 * 256; i += 256) Ws[i >> 8][i & 255] = mW1[i];
    int n0 = blockIdx.x << 3;
    for (int i = tid; i < 8 * 16; i += 256) {
        int r = i >> 4, k = i & 15;
        int n = n0 + r;
        Hs[r][k] = (n < N) ? (hraw[n * 16 + k] * st[k] + st[16 + k]) : 0.f;
    }
    __syncthreads();
    int j = tid;
#pragma unroll
    for (int r = 0; r < 8; r++) {
        int n = n0 + r;
        if (n >= N) break;
        float u = 0.f, v = 0.f;
#pragma unroll
        for (int k = 0; k < 16; k++) {
            float hval = Hs[r][k];
            u += hval * Ws[k][j];
            v += hval * Ws[16 + k][j];
        }
        uvh[n * 512 + j] = __float2half(u);
        uvh[n * 512 + 256 + j] = __float2half(v);
    }
}

// ---------------- edge MLP stats (fp16 uv gather) ----------------

__global__ __launch_bounds__(256) void edge_stats(const ushort* __restrict__ uvp,
                                                  const int* __restrict__ row,
                                                  const int* __restrict__ col,
                                                  float* __restrict__ S, int E) {
    __shared__ float red[4][1024];
    int tid = threadIdx.x;
    int w = tid >> 6, l = tid & 63;
    int l4 = l << 2;
    float s1[4] = {0, 0, 0, 0}, q1[4] = {0, 0, 0, 0};
    float s2[4] = {0, 0, 0, 0}, q2[4] = {0, 0, 0, 0};
    int gw = blockIdx.x * 4 + w;
    int nw = gridDim.x * 4;
    for (int e = gw; e < E; e += nw) {
        int r = row[e], c = col[e];
        H4 ur, vr, uc, vc;
        ur.u = *(const ushort4*)(uvp + r * 512 + l4);
        vr.u = *(const ushort4*)(uvp + r * 512 + 256 + l4);
        uc.u = *(const ushort4*)(uvp + c * 512 + l4);
        vc.u = *(const ushort4*)(uvp + c * 512 + 256 + l4);
#pragma unroll
        for (int j = 0; j < 4; j++) {
            float w1 = __half2float(ur.h[j]) + __half2float(vc.h[j]);
            float w2 = __half2float(vr.h[j]) + __half2float(uc.h[j]);
            s1[j] += w1; q1[j] += w1 * w1;
            s2[j] += w2; q2[j] += w2 * w2;
        }
    }
#pragma unroll
    for (int j = 0; j < 4; j++) {
        red[w][0 * 256 + l4 + j] = s1[j];
        red[w][1 * 256 + l4 + j] = q1[j];
        red[w][2 * 256 + l4 + j] = s2[j];
        red[w][3 * 256 + l4 + j] = q2[j];
    }
    __syncthreads();
    for (int i = tid; i < 1024; i += 256) {
        float v = red[0][i] + red[1][i] + red[2][i] + red[3][i];
        atomicAdd(&S[i], v);
    }
}

__global__ void mlp_finalize(const float* __restrict__ S, const float* __restrict__ g,
                             const float* __restrict__ b, float* __restrict__ ab, int E) {
    int c = threadIdx.x;
    float inv = 1.f / (float)E;
    float m1 = S[c] * inv;
    float v1 = S[256 + c] * inv - m1 * m1;
    float m2 = S[512 + c] * inv;
    float v2 = S[768 + c] * inv - m2 * m2;
    float a1 = g[c] * rsqrtf(v1 + 1e-5f);
    float a2 = g[c] * rsqrtf(v2 + 1e-5f);
    ab[c] = a1;
    ab[256 + c] = b[c] - m1 * a1;
    ab[512 + c] = a2;
    ab[768 + c] = b[c] - m2 * a2;
}

// ---------------- edge MLP output ----------------

__global__ __launch_bounds__(256) void edge_out(const ushort* __restrict__ uvp,
                                                const int* __restrict__ row,
                                                const int* __restrict__ col,
                                                const float* __restrict__ ab,
                                                const float* __restrict__ mW2,
                                                const float* __restrict__ mb2,
                                                float* __restrict__ out, int E) {
    int tid = threadIdx.x;
    int w = tid >> 6, l = tid & 63;
    int l4 = l << 2;
    float4 A1 = *(const float4*)(ab + l4);
    float4 B1 = *(const float4*)(ab + 256 + l4);
    float4 A2 = *(const float4*)(ab + 512 + l4);
    float4 B2 = *(const float4*)(ab + 768 + l4);
    float4 W2 = *(const float4*)(mW2 + l4);
    float mb2v = mb2[0];
    int gw = blockIdx.x * 4 + w;
    int nw = gridDim.x * 4;
    for (int e = gw; e < E; e += nw) {
        int r = row[e], c = col[e];
        H4 ur, vr, uc, vc;
        ur.u = *(const ushort4*)(uvp + r * 512 + l4);
        vr.u = *(const ushort4*)(uvp + r * 512 + 256 + l4);
        uc.u = *(const ushort4*)(uvp + c * 512 + l4);
        vc.u = *(const ushort4*)(uvp + c * 512 + 256 + l4);
        float p = 0.f;
        p += fmaxf((__half2float(ur.h[0]) + __half2float(vc.h[0])) * A1.x + B1.x, 0.f) * W2.x;
        p += fmaxf((__half2float(ur.h[1]) + __half2float(vc.h[1])) * A1.y + B1.y, 0.f) * W2.y;
        p += fmaxf((__half2float(ur.h[2]) + __half2float(vc.h[2])) * A1.z + B1.z, 0.f) * W2.z;
        p += fmaxf((__half2float(ur.h[3]) + __half2float(vc.h[3])) * A1.w + B1.w, 0.f) * W2.w;
        p += fmaxf((__half2float(vr.h[0]) + __half2float(uc.h[0])) * A2.x + B2.x, 0.f) * W2.x;
        p += fmaxf((__half2float(vr.h[1]) + __half2float(uc.h[1])) * A2.y + B2.y, 0.f) * W2.y;
        p += fmaxf((__half2float(vr.h[2]) + __half2float(uc.h[2])) * A2.z + B2.z, 0.f) * W2.z;
        p += fmaxf((__half2float(vr.h[3]) + __half2float(uc.h[3])) * A2.w + B2.w, 0.f) * W2.w;
#pragma unroll
        for (int off = 32; off > 0; off >>= 1) p += __shfl_down(p, off);
        if (l == 0) out[e] = 1.f / (1.f + expf(-(0.5f * p + mb2v)));
    }
}

// ---------------- launch ----------------

extern "C" void kernel_launch(void* const* d_in, const int* in_sizes, int n_in,
                              void* d_out, int out_size, void* d_ws, size_t ws_size,
                              hipStream_t stream) {
    const float* x     = (const float*)d_in[0];
    const int*   ei    = (const int*)d_in[1];
    const float* ew    = (const float*)d_in[2];
    const float* W0    = (const float*)d_in[3];
    const float* b0    = (const float*)d_in[4];
    const float* Wm    = (const float*)d_in[5];
    const float* bm    = (const float*)d_in[6];
    const float* Wl    = (const float*)d_in[7];
    const float* bl    = (const float*)d_in[8];
    const float* bn0_g = (const float*)d_in[9];
    const float* bn0_b = (const float*)d_in[10];
    const float* bnm_g = (const float*)d_in[11];
    const float* bnm_b = (const float*)d_in[12];
    const float* bno_g = (const float*)d_in[13];
    const float* bno_b = (const float*)d_in[14];
    const float* mW1   = (const float*)d_in[15];
    const float* mbn_g = (const float*)d_in[17];
    const float* mbn_b = (const float*)d_in[18];
    const float* mW2   = (const float*)d_in[19];
    const float* mb2   = (const float*)d_in[20];
    float* outp = (float*)d_out;

    char* ws = (char*)d_ws;
    int*    counts  = (int*)(ws + OFF_COUNTS);
    int*    cursor  = (int*)(ws + OFF_CURSOR);
    float*  w_in    = (float*)(ws + OFF_WIN);
    float*  stats   = (float*)(ws + OFF_STATS);
    float*  S       = (float*)(ws + OFF_S);
    float*  st      = (float*)(ws + OFF_ST);
    float*  ab      = (float*)(ws + OFF_AB);
    int*    offsets = (int*)(ws + OFF_OFFSETS);
    int*    srow    = (int*)(ws + OFF_SROW);
    float*  sew     = (float*)(ws + OFF_SEW);
    float*  tmp16   = (float*)(ws + OFF_TMP16);
    float*  hraw    = (float*)(ws + OFF_HRAW);
    ushort* Wthi    = (ushort*)(ws + OFF_WTHI);
    ushort* Wtlo    = (ushort*)(ws + OFF_WTLO);
    __half* bufQ    = (__half*)(ws + OFF_BUFQ);
    float*  bufP    = (float*)(ws + OFF_BUFP);
    float*  agg2    = tmp16;                    // layer0 aggregate (reuse)
    __half* uvh     = (__half*)(ws + OFF_BUFP); // uv aliases bufP (dead by then)

    const int N = NNODES, E = NEDGES;

    hipMemsetAsync(ws, 0, ZERO_END, stream);

    // CSR build + weight preconvert
    hist_kernel<<<1024, 256, 0, stream>>>(ei, ew, counts, w_in, E);
    wsplit<<<640, 256, 0, stream>>>(Wm, Wthi, Wtlo);
    scan_kernel<<<1, 1024, 0, stream>>>(counts, offsets, N);
    scatter_kernel<<<1024, 256, 0, stream>>>(ei, ew, offsets, cursor, srow, sew, E);

    // ---- layer 0 ----
    colstats_small<<<128, 256, 0, stream>>>(x, stats + 0 * 512, 2, N);
    bn_finalize<<<1, 256, 0, stream>>>(stats + 0 * 512, bn0_g, bn0_b, st, 2, N);
    spmm_small<<<(N + 127) / 128, 256, 0, stream>>>(x, srow, sew, offsets, agg2, 2, N, 0);
    layer0_fin<<<(N + 3) / 4, 256, 0, stream>>>(agg2, w_in, st, W0, b0, bufP, N);

    // ---- 10 mid layers ----
    for (int i = 0; i < 10; i++) {
        colstats256<<<512, 256, 0, stream>>>(bufP, stats + (1 + i) * 512, N);
        bn_finalize<<<1, 256, 0, stream>>>(stats + (1 + i) * 512, bnm_g + i * 256,
                                           bnm_b + i * 256, st, 256, N);
        gemm_mfma<<<dim3((N + 127) / 128, 2), 256, 0, stream>>>(
            bufP, Wthi + i * 65536, Wtlo + i * 65536, bm + i * 256, st, bufQ, N);
        spmm_f16<<<(N + 3) / 4, 256, 0, stream>>>(bufQ, srow, sew, offsets, bufP, N);
    }

    // ---- last GCN layer (256 -> 16) ----
    colstats256<<<512, 256, 0, stream>>>(bufP, stats + 11 * 512, N);
    bn_finalize<<<1, 256, 0, stream>>>(stats + 11 * 512, bnm_g + 10 * 256,
                                       bnm_b + 10 * 256, st, 256, N);
    gemm16<<<(N + 15) / 16, 256, 0, stream>>>(bufP, Wl, bl, st, tmp16, N);
    spmm_small<<<(N + 15) / 16, 256, 0, stream>>>(tmp16, srow, sew, offsets, hraw, 16, N, 1);

    // ---- final BN + u/v precompute (fp16) ----
    colstats_small<<<512, 256, 0, stream>>>(hraw, stats + 12 * 512, 16, N);
    bn_finalize<<<1, 256, 0, stream>>>(stats + 12 * 512, bno_g, bno_b, st, 16, N);
    uv_kernel<<<(N + 7) / 8, 256, 0, stream>>>(hraw, st, mW1, uvh, N);

    // ---- edge MLP ----
    edge_stats<<<1024, 256, 0, stream>>>((const ushort*)uvh, ei, ei + E, S, E);
    mlp_finalize<<<1, 256, 0, stream>>>(S, mbn_g, mbn_b, ab, E);
    edge_out<<<1024, 256, 0, stream>>>((const ushort*)uvh, ei, ei + E, ab, mW2, mb2, outp, E);
}

// Round 3
// 2245.104 us; speedup vs baseline: 2.0633x; 1.3545x over previous
//
#include <hip/hip_runtime.h>
#include <hip/hip_bf16.h>
#include <hip/hip_fp16.h>
#include <math.h>

#define NNODES 50000
#define NEDGES 800000

// ---------------- workspace layout (bytes) ----------------
#define OFF_COUNTS   0ull                      // int[50000]
#define OFF_CURSOR   200704ull                 // int[50000]
#define OFF_WIN      401408ull                 // float[50000]
#define OFF_STATS    602112ull                 // float[13*512]
#define OFF_S        628736ull                 // float[1024]
#define ZERO_END     632832ull
#define OFF_ST       632832ull                 // float[512]
#define OFF_AB       634880ull                 // float[1024]
#define OFF_OFFSETS  638976ull                 // int[50001]
#define OFF_SROW     840704ull                 // int[800000]
#define OFF_SEW      4040704ull                // float[800000]
#define OFF_TMP16    7240704ull                // float[50000*16]
#define OFF_HRAW     10440704ull               // float[50000*16]
#define OFF_WTHI     13640704ull               // ushort[10*256*256] bf16 hi (transposed)
#define OFF_WTLO     14951424ull               // ushort[10*256*256] bf16 lo
#define OFF_BUFQ     16262144ull               // half[50000*256]
#define OFF_BUFP     41862144ull               // float[50000*256]; uv (half[50000*512]) aliases

typedef __attribute__((ext_vector_type(8))) short bf16x8;
typedef __attribute__((ext_vector_type(4))) float f32x4;

union H4 { ushort4 u; __half h[4]; };

static __device__ inline ushort f2bf_rne(float f) {
    __hip_bfloat16 b = __float2bfloat16(f);
    union { __hip_bfloat16 bb; ushort u; } cv; cv.bb = b; return cv.u;
}

// split f into bf16 hi (truncate) + bf16 lo (RNE of remainder)
static __device__ inline void bf_split(float f, ushort& hi, ushort& lo) {
    unsigned u = __float_as_uint(f);
    hi = (ushort)(u >> 16);
    float rem = f - __uint_as_float(u & 0xffff0000u);
    lo = f2bf_rne(rem);
}

// ---------------- preprocessing ----------------

__global__ void hist_kernel(const int* __restrict__ ei, const float* __restrict__ ew,
                            int* __restrict__ counts, float* __restrict__ w_in, int E) {
    for (int i = blockIdx.x * blockDim.x + threadIdx.x; i < E; i += gridDim.x * blockDim.x) {
        int c = ei[E + i];
        atomicAdd(&counts[c], 1);
        atomicAdd(&w_in[c], ew[i]);
    }
}

__global__ void scan_kernel(const int* __restrict__ counts, int* __restrict__ offsets, int N) {
    __shared__ int wsum[16];
    __shared__ int carry_s;
    int tid = threadIdx.x;
    int lane = tid & 63, w = tid >> 6;
    if (tid == 0) carry_s = 0;
    __syncthreads();
    for (int base = 0; base < N; base += 1024) {
        int v = (base + tid < N) ? counts[base + tid] : 0;
        int x = v;
#pragma unroll
        for (int off = 1; off < 64; off <<= 1) {
            int y = __shfl_up(x, off);
            if (lane >= off) x += y;
        }
        if (lane == 63) wsum[w] = x;
        __syncthreads();
        if (w == 0 && lane < 16) {
            int s = wsum[lane];
#pragma unroll
            for (int off = 1; off < 16; off <<= 1) {
                int y = __shfl_up(s, off);
                if (lane >= off) s += y;
            }
            wsum[lane] = s;
        }
        __syncthreads();
        int wbase = (w > 0) ? wsum[w - 1] : 0;
        int incl = carry_s + wbase + x;
        if (base + tid < N) offsets[base + tid] = incl - v;
        __syncthreads();
        if (tid == 0) carry_s += wsum[15];
        __syncthreads();
    }
    if (tid == 0) offsets[N] = carry_s;
}

__global__ void scatter_kernel(const int* __restrict__ ei, const float* __restrict__ ew,
                               const int* __restrict__ offsets, int* __restrict__ cursor,
                               int* __restrict__ srow, float* __restrict__ sew, int E) {
    for (int i = blockIdx.x * blockDim.x + threadIdx.x; i < E; i += gridDim.x * blockDim.x) {
        int c = ei[E + i];
        int p = offsets[c] + atomicAdd(&cursor[c], 1);
        srow[p] = ei[i];
        sew[p] = ew[i];
    }
}

// ---------------- weight preconvert: Wt_hi/lo[n][k] = split(Wm[k][n]) ----------------

__global__ __launch_bounds__(256) void wsplit(const float* __restrict__ Wm,
                                              ushort* __restrict__ hi, ushort* __restrict__ lo) {
    __shared__ float tile[32][33];
    int b = blockIdx.x;
    int layer = b >> 6, t = b & 63;
    int tk = (t >> 3) << 5, tn = (t & 7) << 5;
    int tid = threadIdx.x;
    int r = tid >> 5, c = tid & 31;
    const float* W = Wm + layer * 65536;
#pragma unroll
    for (int i = 0; i < 4; i++) tile[r + i * 8][c] = W[(tk + r + i * 8) * 256 + tn + c];
    __syncthreads();
#pragma unroll
    for (int i = 0; i < 4; i++) {
        int n = tn + r + i * 8, k = tk + c;
        float f = tile[c][r + i * 8];
        ushort h, l;
        bf_split(f, h, l);
        hi[layer * 65536 + n * 256 + k] = h;
        lo[layer * 65536 + n * 256 + k] = l;
    }
}

// ---------------- BN column stats ----------------

// 256-wide (one column per thread; cross-block contention only)
__global__ __launch_bounds__(256) void colstats256(const float* __restrict__ h,
                                                   float* __restrict__ sums, int M) {
    int c = threadIdx.x;
    float s = 0.f, q = 0.f;
    for (int r = blockIdx.x; r < M; r += gridDim.x) {
        float v = h[r * 256 + c];
        s += v; q += v * v;
    }
    atomicAdd(&sums[c], s);
    atomicAdd(&sums[256 + c], q);
}

// small-C (C power of 2, C<=64): wave-reduce before atomics
__global__ __launch_bounds__(256) void colstats_wr(const float* __restrict__ h,
                                                   float* __restrict__ sums, int C, int M) {
    int gtid = blockIdx.x * blockDim.x + threadIdx.x;
    int lane = threadIdx.x & 63;
    int c = gtid % C;                // C | 256 so c == lane % C
    int r = gtid / C;
    int stride = (gridDim.x * blockDim.x) / C;
    float s = 0.f, q = 0.f;
    for (; r < M; r += stride) {
        float v = h[r * C + c];
        s += v; q += v * v;
    }
    for (int m = 32; m >= C; m >>= 1) {
        s += __shfl_xor(s, m);
        q += __shfl_xor(q, m);
    }
    if (lane < C) {
        atomicAdd(&sums[c], s);
        atomicAdd(&sums[C + c], q);
    }
}

__global__ void bn_finalize(const float* __restrict__ sums, const float* __restrict__ g,
                            const float* __restrict__ b, float* __restrict__ st, int C, int M) {
    int c = threadIdx.x;
    if (c >= C) return;
    float mean = sums[c] / (float)M;
    float var  = sums[C + c] / (float)M - mean * mean;
    float sc = g[c] * rsqrtf(var + 1e-5f);
    st[c] = sc;
    st[C + c] = b[c] - mean * sc;
}

// ---------------- MFMA GEMM (bf16x3): out_f16 = (bn(H))@W + bias ----------------
// BN finalize fused in prologue. grid (ceil(M/128), 2); 4 waves; wave: 32 rows x 128 cols

__global__ __launch_bounds__(256) void gemm_mfma(const float* __restrict__ H,
                                                 const ushort* __restrict__ Wthi,
                                                 const ushort* __restrict__ Wtlo,
                                                 const float* __restrict__ bias,
                                                 const float* __restrict__ stats,
                                                 const float* __restrict__ g,
                                                 const float* __restrict__ b,
                                                 __half* __restrict__ out, int M) {
    __shared__ __attribute__((aligned(16))) ushort Ahi[128][40];
    __shared__ __attribute__((aligned(16))) ushort Alo[128][40];
    __shared__ __attribute__((aligned(16))) ushort Bhi[128][40];
    __shared__ __attribute__((aligned(16))) ushort Blo[128][40];
    __shared__ __attribute__((aligned(16))) float st_s[512];
    int tid = threadIdx.x;
    int wid = tid >> 6, lane = tid & 63;
    int m0 = blockIdx.x * 128;
    int n0 = blockIdx.y * 128;

    // fused bn_finalize: st_s[c] = scale, st_s[256+c] = shift
    {
        float invM = 1.f / (float)M;
        float mean = stats[tid] * invM;
        float var  = stats[256 + tid] * invM - mean * mean;
        float sc = g[tid] * rsqrtf(var + 1e-5f);
        st_s[tid] = sc;
        st_s[256 + tid] = b[tid] - mean * sc;
    }
    __syncthreads();

    f32x4 acc[2][8];
#pragma unroll
    for (int m = 0; m < 2; m++)
#pragma unroll
        for (int n = 0; n < 8; n++) acc[m][n] = (f32x4){0.f, 0.f, 0.f, 0.f};

    int sr = tid >> 3;               // 0..31
    int kq = (tid & 7) << 2;         // 0,4,...,28
    int fr = lane & 15;
    int qo = (lane >> 4) << 3;       // elem offset 0,8,16,24
    int mrow = wid << 5;

    for (int k0 = 0; k0 < 256; k0 += 32) {
        // stage A (affine + split): 128 rows x 32 k
#pragma unroll
        for (int t = 0; t < 4; t++) {
            int r = sr + t * 32;
            int gr = m0 + r; if (gr >= M) gr = M - 1;
            float4 h4 = *(const float4*)(H + gr * 256 + k0 + kq);
            float4 s4 = *(const float4*)(st_s + k0 + kq);
            float4 t4 = *(const float4*)(st_s + 256 + k0 + kq);
            float a0 = h4.x * s4.x + t4.x;
            float a1 = h4.y * s4.y + t4.y;
            float a2 = h4.z * s4.z + t4.z;
            float a3 = h4.w * s4.w + t4.w;
            ushort4 vh, vl;
            bf_split(a0, vh.x, vl.x);
            bf_split(a1, vh.y, vl.y);
            bf_split(a2, vh.z, vl.z);
            bf_split(a3, vh.w, vl.w);
            *(ushort4*)&Ahi[r][kq] = vh;
            *(ushort4*)&Alo[r][kq] = vl;
        }
        // stage B
#pragma unroll
        for (int t = 0; t < 4; t++) {
            int n = sr + t * 32;
            ushort4 bh = *(const ushort4*)(Wthi + (n0 + n) * 256 + k0 + kq);
            ushort4 bl = *(const ushort4*)(Wtlo + (n0 + n) * 256 + k0 + kq);
            *(ushort4*)&Bhi[n][kq] = bh;
            *(ushort4*)&Blo[n][kq] = bl;
        }
        __syncthreads();

        bf16x8 ah0 = *(const bf16x8*)&Ahi[mrow + fr][qo];
        bf16x8 ah1 = *(const bf16x8*)&Ahi[mrow + 16 + fr][qo];
        bf16x8 al0 = *(const bf16x8*)&Alo[mrow + fr][qo];
        bf16x8 al1 = *(const bf16x8*)&Alo[mrow + 16 + fr][qo];
#pragma unroll
        for (int nt = 0; nt < 8; nt++) {
            bf16x8 bh = *(const bf16x8*)&Bhi[nt * 16 + fr][qo];
            bf16x8 bl = *(const bf16x8*)&Blo[nt * 16 + fr][qo];
            acc[0][nt] = __builtin_amdgcn_mfma_f32_16x16x32_bf16(ah0, bh, acc[0][nt], 0, 0, 0);
            acc[1][nt] = __builtin_amdgcn_mfma_f32_16x16x32_bf16(ah1, bh, acc[1][nt], 0, 0, 0);
            acc[0][nt] = __builtin_amdgcn_mfma_f32_16x16x32_bf16(al0, bh, acc[0][nt], 0, 0, 0);
            acc[1][nt] = __builtin_amdgcn_mfma_f32_16x16x32_bf16(al1, bh, acc[1][nt], 0, 0, 0);
            acc[0][nt] = __builtin_amdgcn_mfma_f32_16x16x32_bf16(ah0, bl, acc[0][nt], 0, 0, 0);
            acc[1][nt] = __builtin_amdgcn_mfma_f32_16x16x32_bf16(ah1, bl, acc[1][nt], 0, 0, 0);
        }
        __syncthreads();
    }

    // epilogue: C/D layout col=lane&15, row=(lane>>4)*4+j
#pragma unroll
    for (int mt = 0; mt < 2; mt++) {
        int gmb = m0 + mrow + mt * 16 + ((lane >> 4) << 2);
#pragma unroll
        for (int nt = 0; nt < 8; nt++) {
            int gn = n0 + nt * 16 + fr;
            float bv = bias[gn];
#pragma unroll
            for (int j = 0; j < 4; j++) {
                int gm = gmb + j;
                if (gm < M) out[gm * 256 + gn] = __float2half(acc[mt][nt][j] + bv);
            }
        }
    }
}

// ---------------- SpMM fp16 gather (wave per node, 16-deep) ----------------

__global__ __launch_bounds__(256) void spmm_f16(const __half* __restrict__ T,
                                                const int* __restrict__ srow,
                                                const float* __restrict__ sew,
                                                const int* __restrict__ off,
                                                float* __restrict__ outp, int N) {
    int wid = threadIdx.x >> 6, lane = threadIdx.x & 63;
    int n = blockIdx.x * 4 + wid;
    if (n >= N) return;
    int e0 = off[n], e1 = off[n + 1];
    float4 acc = {0.f, 0.f, 0.f, 0.f};
    const ushort* Tu = (const ushort*)T;
    int l4 = lane << 2;
    int e = e0;
    for (; e + 15 < e1; e += 16) {
        int r[16]; float w[16]; H4 v[16];
#pragma unroll
        for (int i = 0; i < 16; i++) { r[i] = srow[e + i]; w[i] = sew[e + i]; }
#pragma unroll
        for (int i = 0; i < 16; i++) v[i].u = *(const ushort4*)(Tu + r[i] * 256 + l4);
#pragma unroll
        for (int i = 0; i < 16; i++) {
            acc.x += w[i] * __half2float(v[i].h[0]);
            acc.y += w[i] * __half2float(v[i].h[1]);
            acc.z += w[i] * __half2float(v[i].h[2]);
            acc.w += w[i] * __half2float(v[i].h[3]);
        }
    }
    for (; e + 3 < e1; e += 4) {
        int r[4]; float w[4]; H4 v[4];
#pragma unroll
        for (int i = 0; i < 4; i++) { r[i] = srow[e + i]; w[i] = sew[e + i]; }
#pragma unroll
        for (int i = 0; i < 4; i++) v[i].u = *(const ushort4*)(Tu + r[i] * 256 + l4);
#pragma unroll
        for (int i = 0; i < 4; i++) {
            acc.x += w[i] * __half2float(v[i].h[0]);
            acc.y += w[i] * __half2float(v[i].h[1]);
            acc.z += w[i] * __half2float(v[i].h[2]);
            acc.w += w[i] * __half2float(v[i].h[3]);
        }
    }
    for (; e < e1; ++e) {
        int rr = srow[e]; float w = sew[e];
        H4 v; v.u = *(const ushort4*)(Tu + rr * 256 + l4);
        acc.x += w * __half2float(v.h[0]);
        acc.y += w * __half2float(v.h[1]);
        acc.z += w * __half2float(v.h[2]);
        acc.w += w * __half2float(v.h[3]);
    }
    acc.x = fmaxf(acc.x, 0.f); acc.y = fmaxf(acc.y, 0.f);
    acc.z = fmaxf(acc.z, 0.f); acc.w = fmaxf(acc.w, 0.f);
    *(float4*)(outp + n * 256 + l4) = acc;
}

__global__ __launch_bounds__(256) void spmm_small(const float* __restrict__ T,
                                                  const int* __restrict__ srow,
                                                  const float* __restrict__ sew,
                                                  const int* __restrict__ off,
                                                  float* __restrict__ out,
                                                  int C, int N, int relu) {
    int npb = blockDim.x / C;
    int local = threadIdx.x / C;
    int c = threadIdx.x % C;
    int n = blockIdx.x * npb + local;
    if (n >= N) return;
    int e0 = off[n], e1 = off[n + 1];
    float acc = 0.f;
    for (int e = e0; e < e1; ++e) acc += sew[e] * T[srow[e] * C + c];
    if (relu) acc = fmaxf(acc, 0.f);
    out[n * C + c] = acc;
}

// ---------------- layer 0 finalize ----------------

__global__ __launch_bounds__(256) void layer0_fin(const float* __restrict__ agg2,
                                                  const float* __restrict__ w_in,
                                                  const float* __restrict__ st,
                                                  const float* __restrict__ W0,
                                                  const float* __restrict__ b0,
                                                  float* __restrict__ h, int N) {
    int j = threadIdx.x;
    float w0j = W0[j], w1j = W0[256 + j], b0j = b0[j];
    float s0 = st[0], s1 = st[1], t0 = st[2], t1 = st[3];
    int n0 = blockIdx.x << 2;
#pragma unroll
    for (int i = 0; i < 4; i++) {
        int n = n0 + i;
        if (n >= N) break;
        float wi = w_in[n];
        float a0 = agg2[n * 2 + 0] * s0 + wi * t0;
        float a1 = agg2[n * 2 + 1] * s1 + wi * t1;
        float v = a0 * w0j + a1 * w1j + wi * b0j;
        h[n * 256 + j] = fmaxf(v, 0.f);
    }
}

// ---------------- last GCN linear: [M,256] x [256,16] ----------------

__global__ __launch_bounds__(256) void gemm16(const float* __restrict__ H,
                                              const float* __restrict__ Wl,
                                              const float* __restrict__ bl,
                                              const float* __restrict__ st,
                                              float* __restrict__ out, int M) {
    __shared__ float Hs[16][256];
    __shared__ float Ws[256][16];
    int tid = threadIdx.x;
    int n0 = blockIdx.x << 4;
    for (int i = tid; i < 4096; i += 256) Ws[i >> 4][i & 15] = Wl[i];
    for (int i = tid; i < 4096; i += 256) {
        int r = i >> 8, k = i & 255;
        int n = n0 + r;
        Hs[r][k] = (n < M) ? (H[n * 256 + k] * st[k] + st[256 + k]) : 0.f;
    }
    __syncthreads();
    int r = tid >> 4, j = tid & 15;
    float acc = bl[j];
    for (int k = 0; k < 256; k++) acc += Hs[r][k] * Ws[k][j];
    if (n0 + r < M) out[(n0 + r) * 16 + j] = acc;
}

// ---------------- u/v precompute (fp16 out) ----------------

__global__ __launch_bounds__(256) void uv_kernel(const float* __restrict__ hraw,
                                                 const float* __restrict__ st,
                                                 const float* __restrict__ mW1,
                                                 __half* __restrict__ uvh, int N) {
    __shared__ float Ws[32][256];
    __shared__ float Hs[8][16];
    int tid = threadIdx.x;
    for (int i = tid; i < 32 * 256; i += 256) Ws[i >> 8][i & 255] = mW1[i];
    int n0 = blockIdx.x << 3;
    for (int i = tid; i < 8 * 16; i += 256) {
        int r = i >> 4, k = i & 15;
        int n = n0 + r;
        Hs[r][k] = (n < N) ? (hraw[n * 16 + k] * st[k] + st[16 + k]) : 0.f;
    }
    __syncthreads();
    int j = tid;
#pragma unroll
    for (int r = 0; r < 8; r++) {
        int n = n0 + r;
        if (n >= N) break;
        float u = 0.f, v = 0.f;
#pragma unroll
        for (int k = 0; k < 16; k++) {
            float hval = Hs[r][k];
            u += hval * Ws[k][j];
            v += hval * Ws[16 + k][j];
        }
        uvh[n * 512 + j] = __float2half(u);
        uvh[n * 512 + 256 + j] = __float2half(v);
    }
}

// ---------------- edge MLP stats (fp16 uv gather) ----------------

__global__ __launch_bounds__(256) void edge_stats(const ushort* __restrict__ uvp,
                                                  const int* __restrict__ row,
                                                  const int* __restrict__ col,
                                                  float* __restrict__ S, int E) {
    __shared__ float red[4][1024];
    int tid = threadIdx.x;
    int w = tid >> 6, l = tid & 63;
    int l4 = l << 2;
    float s1[4] = {0, 0, 0, 0}, q1[4] = {0, 0, 0, 0};
    float s2[4] = {0, 0, 0, 0}, q2[4] = {0, 0, 0, 0};
    int gw = blockIdx.x * 4 + w;
    int nw = gridDim.x * 4;
    for (int e = gw; e < E; e += nw) {
        int r = row[e], c = col[e];
        H4 ur, vr, uc, vc;
        ur.u = *(const ushort4*)(uvp + r * 512 + l4);
        vr.u = *(const ushort4*)(uvp + r * 512 + 256 + l4);
        uc.u = *(const ushort4*)(uvp + c * 512 + l4);
        vc.u = *(const ushort4*)(uvp + c * 512 + 256 + l4);
#pragma unroll
        for (int j = 0; j < 4; j++) {
            float w1 = __half2float(ur.h[j]) + __half2float(vc.h[j]);
            float w2 = __half2float(vr.h[j]) + __half2float(uc.h[j]);
            s1[j] += w1; q1[j] += w1 * w1;
            s2[j] += w2; q2[j] += w2 * w2;
        }
    }
#pragma unroll
    for (int j = 0; j < 4; j++) {
        red[w][0 * 256 + l4 + j] = s1[j];
        red[w][1 * 256 + l4 + j] = q1[j];
        red[w][2 * 256 + l4 + j] = s2[j];
        red[w][3 * 256 + l4 + j] = q2[j];
    }
    __syncthreads();
    for (int i = tid; i < 1024; i += 256) {
        float v = red[0][i] + red[1][i] + red[2][i] + red[3][i];
        atomicAdd(&S[i], v);
    }
}

__global__ void mlp_finalize(const float* __restrict__ S, const float* __restrict__ g,
                             const float* __restrict__ b, float* __restrict__ ab, int E) {
    int c = threadIdx.x;
    float inv = 1.f / (float)E;
    float m1 = S[c] * inv;
    float v1 = S[256 + c] * inv - m1 * m1;
    float m2 = S[512 + c] * inv;
    float v2 = S[768 + c] * inv - m2 * m2;
    float a1 = g[c] * rsqrtf(v1 + 1e-5f);
    float a2 = g[c] * rsqrtf(v2 + 1e-5f);
    ab[c] = a1;
    ab[256 + c] = b[c] - m1 * a1;
    ab[512 + c] = a2;
    ab[768 + c] = b[c] - m2 * a2;
}

// ---------------- edge MLP output ----------------

__global__ __launch_bounds__(256) void edge_out(const ushort* __restrict__ uvp,
                                                const int* __restrict__ row,
                                                const int* __restrict__ col,
                                                const float* __restrict__ ab,
                                                const float* __restrict__ mW2,
                                                const float* __restrict__ mb2,
                                                float* __restrict__ out, int E) {
    int tid = threadIdx.x;
    int w = tid >> 6, l = tid & 63;
    int l4 = l << 2;
    float4 A1 = *(const float4*)(ab + l4);
    float4 B1 = *(const float4*)(ab + 256 + l4);
    float4 A2 = *(const float4*)(ab + 512 + l4);
    float4 B2 = *(const float4*)(ab + 768 + l4);
    float4 W2 = *(const float4*)(mW2 + l4);
    float mb2v = mb2[0];
    int gw = blockIdx.x * 4 + w;
    int nw = gridDim.x * 4;
    for (int e = gw; e < E; e += nw) {
        int r = row[e], c = col[e];
        H4 ur, vr, uc, vc;
        ur.u = *(const ushort4*)(uvp + r * 512 + l4);
        vr.u = *(const ushort4*)(uvp + r * 512 + 256 + l4);
        uc.u = *(const ushort4*)(uvp + c * 512 + l4);
        vc.u = *(const ushort4*)(uvp + c * 512 + 256 + l4);
        float p = 0.f;
        p += fmaxf((__half2float(ur.h[0]) + __half2float(vc.h[0])) * A1.x + B1.x, 0.f) * W2.x;
        p += fmaxf((__half2float(ur.h[1]) + __half2float(vc.h[1])) * A1.y + B1.y, 0.f) * W2.y;
        p += fmaxf((__half2float(ur.h[2]) + __half2float(vc.h[2])) * A1.z + B1.z, 0.f) * W2.z;
        p += fmaxf((__half2float(ur.h[3]) + __half2float(vc.h[3])) * A1.w + B1.w, 0.f) * W2.w;
        p += fmaxf((__half2float(vr.h[0]) + __half2float(uc.h[0])) * A2.x + B2.x, 0.f) * W2.x;
        p += fmaxf((__half2float(vr.h[1]) + __half2float(uc.h[1])) * A2.y + B2.y, 0.f) * W2.y;
        p += fmaxf((__half2float(vr.h[2]) + __half2float(uc.h[2])) * A2.z + B2.z, 0.f) * W2.z;
        p += fmaxf((__half2float(vr.h[3]) + __half2float(uc.h[3])) * A2.w + B2.w, 0.f) * W2.w;
#pragma unroll
        for (int off = 32; off > 0; off >>= 1) p += __shfl_down(p, off);
        if (l == 0) out[e] = 1.f / (1.f + expf(-(0.5f * p + mb2v)));
    }
}

// ---------------- launch ----------------

extern "C" void kernel_launch(void* const* d_in, const int* in_sizes, int n_in,
                              void* d_out, int out_size, void* d_ws, size_t ws_size,
                              hipStream_t stream) {
    const float* x     = (const float*)d_in[0];
    const int*   ei    = (const int*)d_in[1];
    const float* ew    = (const float*)d_in[2];
    const float* W0    = (const float*)d_in[3];
    const float* b0    = (const float*)d_in[4];
    const float* Wm    = (const float*)d_in[5];
    const float* bm    = (const float*)d_in[6];
    const float* Wl    = (const float*)d_in[7];
    const float* bl    = (const float*)d_in[8];
    const float* bn0_g = (const float*)d_in[9];
    const float* bn0_b = (const float*)d_in[10];
    const float* bnm_g = (const float*)d_in[11];
    const float* bnm_b = (const float*)d_in[12];
    const float* bno_g = (const float*)d_in[13];
    const float* bno_b = (const float*)d_in[14];
    const float* mW1   = (const float*)d_in[15];
    const float* mbn_g = (const float*)d_in[17];
    const float* mbn_b = (const float*)d_in[18];
    const float* mW2   = (const float*)d_in[19];
    const float* mb2   = (const float*)d_in[20];
    float* outp = (float*)d_out;

    char* ws = (char*)d_ws;
    int*    counts  = (int*)(ws + OFF_COUNTS);
    int*    cursor  = (int*)(ws + OFF_CURSOR);
    float*  w_in    = (float*)(ws + OFF_WIN);
    float*  stats   = (float*)(ws + OFF_STATS);
    float*  S       = (float*)(ws + OFF_S);
    float*  st      = (float*)(ws + OFF_ST);
    float*  ab      = (float*)(ws + OFF_AB);
    int*    offsets = (int*)(ws + OFF_OFFSETS);
    int*    srow    = (int*)(ws + OFF_SROW);
    float*  sew     = (float*)(ws + OFF_SEW);
    float*  tmp16   = (float*)(ws + OFF_TMP16);
    float*  hraw    = (float*)(ws + OFF_HRAW);
    ushort* Wthi    = (ushort*)(ws + OFF_WTHI);
    ushort* Wtlo    = (ushort*)(ws + OFF_WTLO);
    __half* bufQ    = (__half*)(ws + OFF_BUFQ);
    float*  bufP    = (float*)(ws + OFF_BUFP);
    float*  agg2    = tmp16;                    // layer0 aggregate (reuse)
    __half* uvh     = (__half*)(ws + OFF_BUFP); // uv aliases bufP (dead by then)

    const int N = NNODES, E = NEDGES;

    hipMemsetAsync(ws, 0, ZERO_END, stream);

    // CSR build + weight preconvert
    hist_kernel<<<1024, 256, 0, stream>>>(ei, ew, counts, w_in, E);
    wsplit<<<640, 256, 0, stream>>>(Wm, Wthi, Wtlo);
    scan_kernel<<<1, 1024, 0, stream>>>(counts, offsets, N);
    scatter_kernel<<<1024, 256, 0, stream>>>(ei, ew, offsets, cursor, srow, sew, E);

    // ---- layer 0 ----
    colstats_wr<<<64, 256, 0, stream>>>(x, stats + 0 * 512, 2, N);
    bn_finalize<<<1, 256, 0, stream>>>(stats + 0 * 512, bn0_g, bn0_b, st, 2, N);
    spmm_small<<<(N + 127) / 128, 256, 0, stream>>>(x, srow, sew, offsets, agg2, 2, N, 0);
    layer0_fin<<<(N + 3) / 4, 256, 0, stream>>>(agg2, w_in, st, W0, b0, bufP, N);

    // ---- 10 mid layers ----
    for (int i = 0; i < 10; i++) {
        colstats256<<<512, 256, 0, stream>>>(bufP, stats + (1 + i) * 512, N);
        gemm_mfma<<<dim3((N + 127) / 128, 2), 256, 0, stream>>>(
            bufP, Wthi + i * 65536, Wtlo + i * 65536, bm + i * 256,
            stats + (1 + i) * 512, bnm_g + i * 256, bnm_b + i * 256, bufQ, N);
        spmm_f16<<<(N + 3) / 4, 256, 0, stream>>>(bufQ, srow, sew, offsets, bufP, N);
    }

    // ---- last GCN layer (256 -> 16) ----
    colstats256<<<512, 256, 0, stream>>>(bufP, stats + 11 * 512, N);
    bn_finalize<<<1, 256, 0, stream>>>(stats + 11 * 512, bnm_g + 10 * 256,
                                       bnm_b + 10 * 256, st, 256, N);
    gemm16<<<(N + 15) / 16, 256, 0, stream>>>(bufP, Wl, bl, st, tmp16, N);
    spmm_small<<<(N + 15) / 16, 256, 0, stream>>>(tmp16, srow, sew, offsets, hraw, 16, N, 1);

    // ---- final BN + u/v precompute (fp16) ----
    colstats_wr<<<64, 256, 0, stream>>>(hraw, stats + 12 * 512, 16, N);
    bn_finalize<<<1, 256, 0, stream>>>(stats + 12 * 512, bno_g, bno_b, st, 16, N);
    uv_kernel<<<(N + 7) / 8, 256, 0, stream>>>(hraw, st, mW1, uvh, N);

    // ---- edge MLP ----
    edge_stats<<<1024, 256, 0, stream>>>((const ushort*)uvh, ei, ei + E, S, E);
    mlp_finalize<<<1, 256, 0, stream>>>(S, mbn_g, mbn_b, ab, E);
    edge_out<<<1024, 256, 0, stream>>>((const ushort*)uvh, ei, ei + E, ab, mW2, mb2, outp, E);
}

// Round 4
// 1856.132 us; speedup vs baseline: 2.4957x; 1.2096x over previous
//
#include <hip/hip_runtime.h>
#include <hip/hip_bf16.h>
#include <hip/hip_fp16.h>
#include <math.h>

#define NNODES 50000
#define NEDGES 800000

// ---------------- workspace layout (bytes) ----------------
#define OFF_COUNTS   0ull                      // int[50000]
#define OFF_CURSOR   200704ull                 // int[50000]
#define OFF_WIN      401408ull                 // float[50000]
#define OFF_STATS2   602112ull                 // float[2*512]   (x stats, hraw stats)
#define OFF_STATS8   606208ull                 // float[11*16*512] node-stat partials
#define OFF_S8       966656ull                 // float[16*1024]  edge-mlp stat partials
#define ZERO_END     1032192ull
#define OFF_ST       1032192ull                // float[512]
#define OFF_AB       1034240ull                // float[1024]
#define OFF_OFFSETS  1038336ull                // int[50001]
#define OFF_SROW     1239040ull                // int[800000]
#define OFF_SEW      4439040ull                // float[800000]
#define OFF_EPERM    7639040ull                // int[800000]
#define OFF_TMP16    10839040ull               // float[50000*16]
#define OFF_HRAW     14039040ull               // float[50000*16]
#define OFF_WTHI     17239040ull               // ushort[10*256*256] bf16 hi (transposed)
#define OFF_WTLO     18549760ull               // ushort[10*256*256] bf16 lo
#define OFF_BUFQ     19860480ull               // half[50000*256] gemm out
#define OFF_BUFP     45460480ull               // half[50000*256] h
// uv (half[50000*512] = 51.2 MB) aliases BUFQ..BUFP end (both dead by then)

typedef __attribute__((ext_vector_type(8))) short bf16x8;
typedef __attribute__((ext_vector_type(4))) float f32x4;

union H4 { ushort4 u; __half h[4]; };

static __device__ inline ushort f2bf_rne(float f) {
    __hip_bfloat16 b = __float2bfloat16(f);
    union { __hip_bfloat16 bb; ushort u; } cv; cv.bb = b; return cv.u;
}

// split f into bf16 hi (truncate) + bf16 lo (RNE of remainder)
static __device__ inline void bf_split(float f, ushort& hi, ushort& lo) {
    unsigned u = __float_as_uint(f);
    hi = (ushort)(u >> 16);
    float rem = f - __uint_as_float(u & 0xffff0000u);
    lo = f2bf_rne(rem);
}

// ---------------- preprocessing ----------------

__global__ void hist_kernel(const int* __restrict__ ei, const float* __restrict__ ew,
                            int* __restrict__ counts, float* __restrict__ w_in, int E) {
    for (int i = blockIdx.x * blockDim.x + threadIdx.x; i < E; i += gridDim.x * blockDim.x) {
        int c = ei[E + i];
        atomicAdd(&counts[c], 1);
        atomicAdd(&w_in[c], ew[i]);
    }
}

__global__ void scan_kernel(const int* __restrict__ counts, int* __restrict__ offsets, int N) {
    __shared__ int wsum[16];
    __shared__ int carry_s;
    int tid = threadIdx.x;
    int lane = tid & 63, w = tid >> 6;
    if (tid == 0) carry_s = 0;
    __syncthreads();
    for (int base = 0; base < N; base += 1024) {
        int v = (base + tid < N) ? counts[base + tid] : 0;
        int x = v;
#pragma unroll
        for (int off = 1; off < 64; off <<= 1) {
            int y = __shfl_up(x, off);
            if (lane >= off) x += y;
        }
        if (lane == 63) wsum[w] = x;
        __syncthreads();
        if (w == 0 && lane < 16) {
            int s = wsum[lane];
#pragma unroll
            for (int off = 1; off < 16; off <<= 1) {
                int y = __shfl_up(s, off);
                if (lane >= off) s += y;
            }
            wsum[lane] = s;
        }
        __syncthreads();
        int wbase = (w > 0) ? wsum[w - 1] : 0;
        int incl = carry_s + wbase + x;
        if (base + tid < N) offsets[base + tid] = incl - v;
        __syncthreads();
        if (tid == 0) carry_s += wsum[15];
        __syncthreads();
    }
    if (tid == 0) offsets[N] = carry_s;
}

__global__ void scatter_kernel(const int* __restrict__ ei, const float* __restrict__ ew,
                               const int* __restrict__ offsets, int* __restrict__ cursor,
                               int* __restrict__ srow, float* __restrict__ sew,
                               int* __restrict__ eperm, int E) {
    for (int i = blockIdx.x * blockDim.x + threadIdx.x; i < E; i += gridDim.x * blockDim.x) {
        int c = ei[E + i];
        int p = offsets[c] + atomicAdd(&cursor[c], 1);
        srow[p] = ei[i];
        sew[p] = ew[i];
        eperm[p] = i;
    }
}

// ---------------- weight preconvert ----------------

__global__ __launch_bounds__(256) void wsplit(const float* __restrict__ Wm,
                                              ushort* __restrict__ hi, ushort* __restrict__ lo) {
    __shared__ float tile[32][33];
    int b = blockIdx.x;
    int layer = b >> 6, t = b & 63;
    int tk = (t >> 3) << 5, tn = (t & 7) << 5;
    int tid = threadIdx.x;
    int r = tid >> 5, c = tid & 31;
    const float* W = Wm + layer * 65536;
#pragma unroll
    for (int i = 0; i < 4; i++) tile[r + i * 8][c] = W[(tk + r + i * 8) * 256 + tn + c];
    __syncthreads();
#pragma unroll
    for (int i = 0; i < 4; i++) {
        int n = tn + r + i * 8, k = tk + c;
        float f = tile[c][r + i * 8];
        ushort h, l;
        bf_split(f, h, l);
        hi[layer * 65536 + n * 256 + k] = h;
        lo[layer * 65536 + n * 256 + k] = l;
    }
}

// ---------------- small-C column stats (wave-reduced) ----------------

__global__ __launch_bounds__(256) void colstats_wr(const float* __restrict__ h,
                                                   float* __restrict__ sums, int C, int M) {
    int gtid = blockIdx.x * blockDim.x + threadIdx.x;
    int lane = threadIdx.x & 63;
    int c = gtid % C;
    int r = gtid / C;
    int stride = (gridDim.x * blockDim.x) / C;
    float s = 0.f, q = 0.f;
    for (; r < M; r += stride) {
        float v = h[r * C + c];
        s += v; q += v * v;
    }
    for (int m = 32; m >= C; m >>= 1) {
        s += __shfl_xor(s, m);
        q += __shfl_xor(q, m);
    }
    if (lane < C) {
        atomicAdd(&sums[c], s);
        atomicAdd(&sums[C + c], q);
    }
}

__global__ void bn_finalize(const float* __restrict__ sums, const float* __restrict__ g,
                            const float* __restrict__ b, float* __restrict__ st, int C, int M) {
    int c = threadIdx.x;
    if (c >= C) return;
    float mean = sums[c] / (float)M;
    float var  = sums[C + c] / (float)M - mean * mean;
    float sc = g[c] * rsqrtf(var + 1e-5f);
    st[c] = sc;
    st[C + c] = b[c] - mean * sc;
}

// reduce 16 partials -> st
__global__ void bn_finalize16(const float* __restrict__ sp, const float* __restrict__ g,
                              const float* __restrict__ b, float* __restrict__ st, int M) {
    int c = threadIdx.x;
    float s = 0.f, q = 0.f;
#pragma unroll
    for (int p = 0; p < 16; p++) { s += sp[p * 512 + c]; q += sp[p * 512 + 256 + c]; }
    float mean = s / (float)M;
    float var  = q / (float)M - mean * mean;
    float sc = g[c] * rsqrtf(var + 1e-5f);
    st[c] = sc;
    st[256 + c] = b[c] - mean * sc;
}

// ---------------- MFMA GEMM (bf16x3): out_f16 = bn(H_f16)@W + bias ----------------
// BN finalize (16-partial reduce) fused in prologue. grid (ceil(M/128), 2); 4 waves.

__global__ __launch_bounds__(256) void gemm_mfma(const __half* __restrict__ H,
                                                 const ushort* __restrict__ Wthi,
                                                 const ushort* __restrict__ Wtlo,
                                                 const float* __restrict__ bias,
                                                 const float* __restrict__ sp,
                                                 const float* __restrict__ g,
                                                 const float* __restrict__ b,
                                                 __half* __restrict__ out, int M) {
    __shared__ __attribute__((aligned(16))) ushort Ahi[128][40];
    __shared__ __attribute__((aligned(16))) ushort Alo[128][40];
    __shared__ __attribute__((aligned(16))) ushort Bhi[128][40];
    __shared__ __attribute__((aligned(16))) ushort Blo[128][40];
    __shared__ __attribute__((aligned(16))) float st_s[512];
    int tid = threadIdx.x;
    int wid = tid >> 6, lane = tid & 63;
    int m0 = blockIdx.x * 128;
    int n0 = blockIdx.y * 128;
    const ushort* Hu = (const ushort*)H;

    // fused 16-partial reduce + bn_finalize
    {
        float s = 0.f, q = 0.f;
#pragma unroll
        for (int p = 0; p < 16; p++) { s += sp[p * 512 + tid]; q += sp[p * 512 + 256 + tid]; }
        float invM = 1.f / (float)M;
        float mean = s * invM;
        float var  = q * invM - mean * mean;
        float sc = g[tid] * rsqrtf(var + 1e-5f);
        st_s[tid] = sc;
        st_s[256 + tid] = b[tid] - mean * sc;
    }
    __syncthreads();

    f32x4 acc[2][8];
#pragma unroll
    for (int m = 0; m < 2; m++)
#pragma unroll
        for (int n = 0; n < 8; n++) acc[m][n] = (f32x4){0.f, 0.f, 0.f, 0.f};

    int sr = tid >> 3;               // 0..31
    int kq = (tid & 7) << 2;         // 0,4,...,28
    int fr = lane & 15;
    int qo = (lane >> 4) << 3;
    int mrow = wid << 5;

    for (int k0 = 0; k0 < 256; k0 += 32) {
#pragma unroll
        for (int t = 0; t < 4; t++) {
            int r = sr + t * 32;
            int gr = m0 + r; if (gr >= M) gr = M - 1;
            H4 h4; h4.u = *(const ushort4*)(Hu + gr * 256 + k0 + kq);
            float4 s4 = *(const float4*)(st_s + k0 + kq);
            float4 t4 = *(const float4*)(st_s + 256 + k0 + kq);
            float a0 = __half2float(h4.h[0]) * s4.x + t4.x;
            float a1 = __half2float(h4.h[1]) * s4.y + t4.y;
            float a2 = __half2float(h4.h[2]) * s4.z + t4.z;
            float a3 = __half2float(h4.h[3]) * s4.w + t4.w;
            ushort4 vh, vl;
            bf_split(a0, vh.x, vl.x);
            bf_split(a1, vh.y, vl.y);
            bf_split(a2, vh.z, vl.z);
            bf_split(a3, vh.w, vl.w);
            *(ushort4*)&Ahi[r][kq] = vh;
            *(ushort4*)&Alo[r][kq] = vl;
        }
#pragma unroll
        for (int t = 0; t < 4; t++) {
            int n = sr + t * 32;
            ushort4 bh = *(const ushort4*)(Wthi + (n0 + n) * 256 + k0 + kq);
            ushort4 bl = *(const ushort4*)(Wtlo + (n0 + n) * 256 + k0 + kq);
            *(ushort4*)&Bhi[n][kq] = bh;
            *(ushort4*)&Blo[n][kq] = bl;
        }
        __syncthreads();

        bf16x8 ah0 = *(const bf16x8*)&Ahi[mrow + fr][qo];
        bf16x8 ah1 = *(const bf16x8*)&Ahi[mrow + 16 + fr][qo];
        bf16x8 al0 = *(const bf16x8*)&Alo[mrow + fr][qo];
        bf16x8 al1 = *(const bf16x8*)&Alo[mrow + 16 + fr][qo];
#pragma unroll
        for (int nt = 0; nt < 8; nt++) {
            bf16x8 bh = *(const bf16x8*)&Bhi[nt * 16 + fr][qo];
            bf16x8 bl = *(const bf16x8*)&Blo[nt * 16 + fr][qo];
            acc[0][nt] = __builtin_amdgcn_mfma_f32_16x16x32_bf16(ah0, bh, acc[0][nt], 0, 0, 0);
            acc[1][nt] = __builtin_amdgcn_mfma_f32_16x16x32_bf16(ah1, bh, acc[1][nt], 0, 0, 0);
            acc[0][nt] = __builtin_amdgcn_mfma_f32_16x16x32_bf16(al0, bh, acc[0][nt], 0, 0, 0);
            acc[1][nt] = __builtin_amdgcn_mfma_f32_16x16x32_bf16(al1, bh, acc[1][nt], 0, 0, 0);
            acc[0][nt] = __builtin_amdgcn_mfma_f32_16x16x32_bf16(ah0, bl, acc[0][nt], 0, 0, 0);
            acc[1][nt] = __builtin_amdgcn_mfma_f32_16x16x32_bf16(ah1, bl, acc[1][nt], 0, 0, 0);
        }
        __syncthreads();
    }

#pragma unroll
    for (int mt = 0; mt < 2; mt++) {
        int gmb = m0 + mrow + mt * 16 + ((lane >> 4) << 2);
#pragma unroll
        for (int nt = 0; nt < 8; nt++) {
            int gn = n0 + nt * 16 + fr;
            float bv = bias[gn];
#pragma unroll
            for (int j = 0; j < 4; j++) {
                int gm = gmb + j;
                if (gm < M) out[gm * 256 + gn] = __float2half(acc[mt][nt][j] + bv);
            }
        }
    }
}

// ---------------- SpMM fp16 gather + fused column stats ----------------
// grid-stride wave-per-node; stats -> 16-way-spread partials

__global__ __launch_bounds__(256) void spmm_f16s(const __half* __restrict__ T,
                                                 const int* __restrict__ srow,
                                                 const float* __restrict__ sew,
                                                 const int* __restrict__ off,
                                                 __half* __restrict__ outp,
                                                 float* __restrict__ sp, int N) {
    __shared__ float red[4][512];
    int tid = threadIdx.x;
    int wid = tid >> 6, lane = tid & 63;
    int l4 = lane << 2;
    int gw = blockIdx.x * 4 + wid, nw = gridDim.x * 4;
    const ushort* Tu = (const ushort*)T;
    ushort* Ou = (ushort*)outp;
    float cs[4] = {0, 0, 0, 0}, cq[4] = {0, 0, 0, 0};
    for (int n = gw; n < N; n += nw) {
        int e0 = off[n], e1 = off[n + 1];
        float4 acc = {0.f, 0.f, 0.f, 0.f};
        int e = e0;
        for (; e + 7 < e1; e += 8) {
            int r[8]; float w[8]; H4 v[8];
#pragma unroll
            for (int i = 0; i < 8; i++) { r[i] = srow[e + i]; w[i] = sew[e + i]; }
#pragma unroll
            for (int i = 0; i < 8; i++) v[i].u = *(const ushort4*)(Tu + r[i] * 256 + l4);
#pragma unroll
            for (int i = 0; i < 8; i++) {
                acc.x += w[i] * __half2float(v[i].h[0]);
                acc.y += w[i] * __half2float(v[i].h[1]);
                acc.z += w[i] * __half2float(v[i].h[2]);
                acc.w += w[i] * __half2float(v[i].h[3]);
            }
        }
        for (; e < e1; ++e) {
            int rr = srow[e]; float w = sew[e];
            H4 v; v.u = *(const ushort4*)(Tu + rr * 256 + l4);
            acc.x += w * __half2float(v.h[0]);
            acc.y += w * __half2float(v.h[1]);
            acc.z += w * __half2float(v.h[2]);
            acc.w += w * __half2float(v.h[3]);
        }
        acc.x = fmaxf(acc.x, 0.f); acc.y = fmaxf(acc.y, 0.f);
        acc.z = fmaxf(acc.z, 0.f); acc.w = fmaxf(acc.w, 0.f);
        H4 o;
        o.h[0] = __float2half(acc.x); o.h[1] = __float2half(acc.y);
        o.h[2] = __float2half(acc.z); o.h[3] = __float2half(acc.w);
        *(ushort4*)(Ou + n * 256 + l4) = o.u;
        cs[0] += acc.x; cq[0] += acc.x * acc.x;
        cs[1] += acc.y; cq[1] += acc.y * acc.y;
        cs[2] += acc.z; cq[2] += acc.z * acc.z;
        cs[3] += acc.w; cq[3] += acc.w * acc.w;
    }
#pragma unroll
    for (int j = 0; j < 4; j++) {
        red[wid][l4 + j] = cs[j];
        red[wid][256 + l4 + j] = cq[j];
    }
    __syncthreads();
    float* dst = sp + (blockIdx.x & 15) * 512;
    for (int i = tid; i < 512; i += 256)
        atomicAdd(&dst[i], red[0][i] + red[1][i] + red[2][i] + red[3][i]);
}

__global__ __launch_bounds__(256) void spmm_small(const float* __restrict__ T,
                                                  const int* __restrict__ srow,
                                                  const float* __restrict__ sew,
                                                  const int* __restrict__ off,
                                                  float* __restrict__ out,
                                                  int C, int N, int relu) {
    int npb = blockDim.x / C;
    int local = threadIdx.x / C;
    int c = threadIdx.x % C;
    int n = blockIdx.x * npb + local;
    if (n >= N) return;
    int e0 = off[n], e1 = off[n + 1];
    float acc = 0.f;
    for (int e = e0; e < e1; ++e) acc += sew[e] * T[srow[e] * C + c];
    if (relu) acc = fmaxf(acc, 0.f);
    out[n * C + c] = acc;
}

// ---------------- layer 0 finalize + fused column stats ----------------

__global__ __launch_bounds__(256) void layer0_fin(const float* __restrict__ agg2,
                                                  const float* __restrict__ w_in,
                                                  const float* __restrict__ st,
                                                  const float* __restrict__ W0,
                                                  const float* __restrict__ b0,
                                                  __half* __restrict__ h,
                                                  float* __restrict__ sp, int N) {
    int j = threadIdx.x;
    float w0j = W0[j], w1j = W0[256 + j], b0j = b0[j];
    float s0 = st[0], s1 = st[1], t0 = st[2], t1 = st[3];
    float cs = 0.f, cq = 0.f;
    for (int n = blockIdx.x; n < N; n += gridDim.x) {
        float wi = w_in[n];
        float a0 = agg2[n * 2 + 0] * s0 + wi * t0;
        float a1 = agg2[n * 2 + 1] * s1 + wi * t1;
        float v = fmaxf(a0 * w0j + a1 * w1j + wi * b0j, 0.f);
        h[n * 256 + j] = __float2half(v);
        cs += v; cq += v * v;
    }
    float* dst = sp + (blockIdx.x & 15) * 512;
    atomicAdd(&dst[j], cs);
    atomicAdd(&dst[256 + j], cq);
}

// ---------------- last GCN linear: [M,256]f16 x [256,16] ----------------

__global__ __launch_bounds__(256) void gemm16(const __half* __restrict__ H,
                                              const float* __restrict__ Wl,
                                              const float* __restrict__ bl,
                                              const float* __restrict__ st,
                                              float* __restrict__ out, int M) {
    __shared__ float Hs[16][256];
    __shared__ float Ws[256][16];
    int tid = threadIdx.x;
    int n0 = blockIdx.x << 4;
    const ushort* Hu = (const ushort*)H;
    for (int i = tid; i < 4096; i += 256) Ws[i >> 4][i & 15] = Wl[i];
    for (int i = tid; i < 4096; i += 256) {
        int r = i >> 8, k = i & 255;
        int n = n0 + r;
        float hv = 0.f;
        if (n < M) {
            union { ushort u; __half h; } cv; cv.u = Hu[n * 256 + k];
            hv = __half2float(cv.h) * st[k] + st[256 + k];
        }
        Hs[r][k] = hv;
    }
    __syncthreads();
    int r = tid >> 4, j = tid & 15;
    float acc = bl[j];
    for (int k = 0; k < 256; k++) acc += Hs[r][k] * Ws[k][j];
    if (n0 + r < M) out[(n0 + r) * 16 + j] = acc;
}

// ---------------- u/v precompute (fp16 out) ----------------

__global__ __launch_bounds__(256) void uv_kernel(const float* __restrict__ hraw,
                                                 const float* __restrict__ st,
                                                 const float* __restrict__ mW1,
                                                 __half* __restrict__ uvh, int N) {
    __shared__ float Ws[32][256];
    __shared__ float Hs[8][16];
    int tid = threadIdx.x;
    for (int i = tid; i < 32 * 256; i += 256) Ws[i >> 8][i & 255] = mW1[i];
    int n0 = blockIdx.x << 3;
    for (int i = tid; i < 8 * 16; i += 256) {
        int r = i >> 4, k = i & 15;
        int n = n0 + r;
        Hs[r][k] = (n < N) ? (hraw[n * 16 + k] * st[k] + st[16 + k]) : 0.f;
    }
    __syncthreads();
    int j = tid;
#pragma unroll
    for (int r = 0; r < 8; r++) {
        int n = n0 + r;
        if (n >= N) break;
        float u = 0.f, v = 0.f;
#pragma unroll
        for (int k = 0; k < 16; k++) {
            float hval = Hs[r][k];
            u += hval * Ws[k][j];
            v += hval * Ws[16 + k][j];
        }
        uvh[n * 512 + j] = __float2half(u);
        uvh[n * 512 + 256 + j] = __float2half(v);
    }
}

// ---------------- edge MLP stats, CSR order (wave per dest node) ----------------

__global__ __launch_bounds__(256) void edge_stats_csr(const ushort* __restrict__ uvp,
                                                      const int* __restrict__ srow,
                                                      const int* __restrict__ off,
                                                      float* __restrict__ S8, int N) {
    __shared__ float red[4][1024];
    int tid = threadIdx.x;
    int w = tid >> 6, l = tid & 63;
    int l4 = l << 2;
    float s1[4] = {0, 0, 0, 0}, q1[4] = {0, 0, 0, 0};
    float s2[4] = {0, 0, 0, 0}, q2[4] = {0, 0, 0, 0};
    int gw = blockIdx.x * 4 + w;
    int nw = gridDim.x * 4;
    for (int n = gw; n < N; n += nw) {
        H4 uc4, vc4;
        uc4.u = *(const ushort4*)(uvp + n * 512 + l4);
        vc4.u = *(const ushort4*)(uvp + n * 512 + 256 + l4);
        float uc[4], vc[4];
#pragma unroll
        for (int j = 0; j < 4; j++) { uc[j] = __half2float(uc4.h[j]); vc[j] = __half2float(vc4.h[j]); }
        int e0 = off[n], e1 = off[n + 1];
        int e = e0;
        for (; e + 3 < e1; e += 4) {
            int r[4]; H4 ur[4], vr[4];
#pragma unroll
            for (int i = 0; i < 4; i++) r[i] = srow[e + i];
#pragma unroll
            for (int i = 0; i < 4; i++) {
                ur[i].u = *(const ushort4*)(uvp + r[i] * 512 + l4);
                vr[i].u = *(const ushort4*)(uvp + r[i] * 512 + 256 + l4);
            }
#pragma unroll
            for (int i = 0; i < 4; i++)
#pragma unroll
                for (int j = 0; j < 4; j++) {
                    float w1 = __half2float(ur[i].h[j]) + vc[j];
                    float w2 = __half2float(vr[i].h[j]) + uc[j];
                    s1[j] += w1; q1[j] += w1 * w1;
                    s2[j] += w2; q2[j] += w2 * w2;
                }
        }
        for (; e < e1; ++e) {
            int r = srow[e];
            H4 ur, vr;
            ur.u = *(const ushort4*)(uvp + r * 512 + l4);
            vr.u = *(const ushort4*)(uvp + r * 512 + 256 + l4);
#pragma unroll
            for (int j = 0; j < 4; j++) {
                float w1 = __half2float(ur.h[j]) + vc[j];
                float w2 = __half2float(vr.h[j]) + uc[j];
                s1[j] += w1; q1[j] += w1 * w1;
                s2[j] += w2; q2[j] += w2 * w2;
            }
        }
    }
#pragma unroll
    for (int j = 0; j < 4; j++) {
        red[w][0 * 256 + l4 + j] = s1[j];
        red[w][1 * 256 + l4 + j] = q1[j];
        red[w][2 * 256 + l4 + j] = s2[j];
        red[w][3 * 256 + l4 + j] = q2[j];
    }
    __syncthreads();
    float* dst = S8 + (blockIdx.x & 15) * 1024;
    for (int i = tid; i < 1024; i += 256)
        atomicAdd(&dst[i], red[0][i] + red[1][i] + red[2][i] + red[3][i]);
}

__global__ void mlp_finalize16(const float* __restrict__ S8, const float* __restrict__ g,
                               const float* __restrict__ b, float* __restrict__ ab, int E) {
    int c = threadIdx.x;
    float s1 = 0.f, q1 = 0.f, s2 = 0.f, q2 = 0.f;
#pragma unroll
    for (int p = 0; p < 16; p++) {
        s1 += S8[p * 1024 + c];
        q1 += S8[p * 1024 + 256 + c];
        s2 += S8[p * 1024 + 512 + c];
        q2 += S8[p * 1024 + 768 + c];
    }
    float inv = 1.f / (float)E;
    float m1 = s1 * inv, v1 = q1 * inv - m1 * m1;
    float m2 = s2 * inv, v2 = q2 * inv - m2 * m2;
    float a1 = g[c] * rsqrtf(v1 + 1e-5f);
    float a2 = g[c] * rsqrtf(v2 + 1e-5f);
    ab[c] = a1;
    ab[256 + c] = b[c] - m1 * a1;
    ab[512 + c] = a2;
    ab[768 + c] = b[c] - m2 * a2;
}

// ---------------- edge MLP output, CSR order ----------------

__global__ __launch_bounds__(256) void edge_out_csr(const ushort* __restrict__ uvp,
                                                    const int* __restrict__ srow,
                                                    const int* __restrict__ eperm,
                                                    const int* __restrict__ off,
                                                    const float* __restrict__ ab,
                                                    const float* __restrict__ mW2,
                                                    const float* __restrict__ mb2,
                                                    float* __restrict__ out, int N) {
    int tid = threadIdx.x;
    int w = tid >> 6, l = tid & 63;
    int l4 = l << 2;
    float4 A1 = *(const float4*)(ab + l4);
    float4 B1 = *(const float4*)(ab + 256 + l4);
    float4 A2 = *(const float4*)(ab + 512 + l4);
    float4 B2 = *(const float4*)(ab + 768 + l4);
    float4 W2 = *(const float4*)(mW2 + l4);
    float mb2v = mb2[0];
    int gw = blockIdx.x * 4 + w;
    int nw = gridDim.x * 4;
    for (int n = gw; n < N; n += nw) {
        H4 uc4, vc4;
        uc4.u = *(const ushort4*)(uvp + n * 512 + l4);
        vc4.u = *(const ushort4*)(uvp + n * 512 + 256 + l4);
        float uc[4], vc[4];
#pragma unroll
        for (int j = 0; j < 4; j++) { uc[j] = __half2float(uc4.h[j]); vc[j] = __half2float(vc4.h[j]); }
        int e0 = off[n], e1 = off[n + 1];
        int e = e0;
        for (; e + 1 < e1; e += 2) {
            int r0 = srow[e], r1 = srow[e + 1];
            int eo0 = eperm[e], eo1 = eperm[e + 1];
            H4 ur0, vr0, ur1, vr1;
            ur0.u = *(const ushort4*)(uvp + r0 * 512 + l4);
            vr0.u = *(const ushort4*)(uvp + r0 * 512 + 256 + l4);
            ur1.u = *(const ushort4*)(uvp + r1 * 512 + l4);
            vr1.u = *(const ushort4*)(uvp + r1 * 512 + 256 + l4);
            float p0 = 0.f, p1 = 0.f;
            p0 += fmaxf((__half2float(ur0.h[0]) + vc[0]) * A1.x + B1.x, 0.f) * W2.x;
            p0 += fmaxf((__half2float(ur0.h[1]) + vc[1]) * A1.y + B1.y, 0.f) * W2.y;
            p0 += fmaxf((__half2float(ur0.h[2]) + vc[2]) * A1.z + B1.z, 0.f) * W2.z;
            p0 += fmaxf((__half2float(ur0.h[3]) + vc[3]) * A1.w + B1.w, 0.f) * W2.w;
            p0 += fmaxf((__half2float(vr0.h[0]) + uc[0]) * A2.x + B2.x, 0.f) * W2.x;
            p0 += fmaxf((__half2float(vr0.h[1]) + uc[1]) * A2.y + B2.y, 0.f) * W2.y;
            p0 += fmaxf((__half2float(vr0.h[2]) + uc[2]) * A2.z + B2.z, 0.f) * W2.z;
            p0 += fmaxf((__half2float(vr0.h[3]) + uc[3]) * A2.w + B2.w, 0.f) * W2.w;
            p1 += fmaxf((__half2float(ur1.h[0]) + vc[0]) * A1.x + B1.x, 0.f) * W2.x;
            p1 += fmaxf((__half2float(ur1.h[1]) + vc[1]) * A1.y + B1.y, 0.f) * W2.y;
            p1 += fmaxf((__half2float(ur1.h[2]) + vc[2]) * A1.z + B1.z, 0.f) * W2.z;
            p1 += fmaxf((__half2float(ur1.h[3]) + vc[3]) * A1.w + B1.w, 0.f) * W2.w;
            p1 += fmaxf((__half2float(vr1.h[0]) + uc[0]) * A2.x + B2.x, 0.f) * W2.x;
            p1 += fmaxf((__half2float(vr1.h[1]) + uc[1]) * A2.y + B2.y, 0.f) * W2.y;
            p1 += fmaxf((__half2float(vr1.h[2]) + uc[2]) * A2.z + B2.z, 0.f) * W2.z;
            p1 += fmaxf((__half2float(vr1.h[3]) + uc[3]) * A2.w + B2.w, 0.f) * W2.w;
#pragma unroll
            for (int offm = 32; offm > 0; offm >>= 1) {
                p0 += __shfl_down(p0, offm);
                p1 += __shfl_down(p1, offm);
            }
            if (l == 0) {
                out[eo0] = 1.f / (1.f + expf(-(0.5f * p0 + mb2v)));
                out[eo1] = 1.f / (1.f + expf(-(0.5f * p1 + mb2v)));
            }
        }
        for (; e < e1; ++e) {
            int r = srow[e];
            int eo = eperm[e];
            H4 ur, vr;
            ur.u = *(const ushort4*)(uvp + r * 512 + l4);
            vr.u = *(const ushort4*)(uvp + r * 512 + 256 + l4);
            float p = 0.f;
            p += fmaxf((__half2float(ur.h[0]) + vc[0]) * A1.x + B1.x, 0.f) * W2.x;
            p += fmaxf((__half2float(ur.h[1]) + vc[1]) * A1.y + B1.y, 0.f) * W2.y;
            p += fmaxf((__half2float(ur.h[2]) + vc[2]) * A1.z + B1.z, 0.f) * W2.z;
            p += fmaxf((__half2float(ur.h[3]) + vc[3]) * A1.w + B1.w, 0.f) * W2.w;
            p += fmaxf((__half2float(vr.h[0]) + uc[0]) * A2.x + B2.x, 0.f) * W2.x;
            p += fmaxf((__half2float(vr.h[1]) + uc[1]) * A2.y + B2.y, 0.f) * W2.y;
            p += fmaxf((__half2float(vr.h[2]) + uc[2]) * A2.z + B2.z, 0.f) * W2.z;
            p += fmaxf((__half2float(vr.h[3]) + uc[3]) * A2.w + B2.w, 0.f) * W2.w;
#pragma unroll
            for (int offm = 32; offm > 0; offm >>= 1) p += __shfl_down(p, offm);
            if (l == 0) out[eo] = 1.f / (1.f + expf(-(0.5f * p + mb2v)));
        }
    }
}

// ---------------- launch ----------------

extern "C" void kernel_launch(void* const* d_in, const int* in_sizes, int n_in,
                              void* d_out, int out_size, void* d_ws, size_t ws_size,
                              hipStream_t stream) {
    const float* x     = (const float*)d_in[0];
    const int*   ei    = (const int*)d_in[1];
    const float* ew    = (const float*)d_in[2];
    const float* W0    = (const float*)d_in[3];
    const float* b0    = (const float*)d_in[4];
    const float* Wm    = (const float*)d_in[5];
    const float* bm    = (const float*)d_in[6];
    const float* Wl    = (const float*)d_in[7];
    const float* bl    = (const float*)d_in[8];
    const float* bn0_g = (const float*)d_in[9];
    const float* bn0_b = (const float*)d_in[10];
    const float* bnm_g = (const float*)d_in[11];
    const float* bnm_b = (const float*)d_in[12];
    const float* bno_g = (const float*)d_in[13];
    const float* bno_b = (const float*)d_in[14];
    const float* mW1   = (const float*)d_in[15];
    const float* mbn_g = (const float*)d_in[17];
    const float* mbn_b = (const float*)d_in[18];
    const float* mW2   = (const float*)d_in[19];
    const float* mb2   = (const float*)d_in[20];
    float* outp = (float*)d_out;

    char* ws = (char*)d_ws;
    int*    counts  = (int*)(ws + OFF_COUNTS);
    int*    cursor  = (int*)(ws + OFF_CURSOR);
    float*  w_in    = (float*)(ws + OFF_WIN);
    float*  stats2  = (float*)(ws + OFF_STATS2);
    float*  sp8     = (float*)(ws + OFF_STATS8);
    float*  S8      = (float*)(ws + OFF_S8);
    float*  st      = (float*)(ws + OFF_ST);
    float*  ab      = (float*)(ws + OFF_AB);
    int*    offsets = (int*)(ws + OFF_OFFSETS);
    int*    srow    = (int*)(ws + OFF_SROW);
    float*  sew     = (float*)(ws + OFF_SEW);
    int*    eperm   = (int*)(ws + OFF_EPERM);
    float*  tmp16   = (float*)(ws + OFF_TMP16);
    float*  hraw    = (float*)(ws + OFF_HRAW);
    ushort* Wthi    = (ushort*)(ws + OFF_WTHI);
    ushort* Wtlo    = (ushort*)(ws + OFF_WTLO);
    __half* bufQ    = (__half*)(ws + OFF_BUFQ);
    __half* bufP    = (__half*)(ws + OFF_BUFP);
    float*  agg2    = tmp16;                    // layer0 aggregate (reuse)
    __half* uvh     = (__half*)(ws + OFF_BUFQ); // uv spans bufQ+bufP (dead by then)

    const int N = NNODES, E = NEDGES;

    hipMemsetAsync(ws, 0, ZERO_END, stream);

    // CSR build + weight preconvert
    hist_kernel<<<1024, 256, 0, stream>>>(ei, ew, counts, w_in, E);
    wsplit<<<640, 256, 0, stream>>>(Wm, Wthi, Wtlo);
    scan_kernel<<<1, 1024, 0, stream>>>(counts, offsets, N);
    scatter_kernel<<<1024, 256, 0, stream>>>(ei, ew, offsets, cursor, srow, sew, eperm, E);

    // ---- layer 0 ----
    colstats_wr<<<64, 256, 0, stream>>>(x, stats2 + 0 * 512, 2, N);
    bn_finalize<<<1, 256, 0, stream>>>(stats2 + 0 * 512, bn0_g, bn0_b, st, 2, N);
    spmm_small<<<(N + 127) / 128, 256, 0, stream>>>(x, srow, sew, offsets, agg2, 2, N, 0);
    layer0_fin<<<512, 256, 0, stream>>>(agg2, w_in, st, W0, b0, bufP, sp8 + 0 * 8192, N);

    // ---- 10 mid layers ----
    for (int i = 0; i < 10; i++) {
        gemm_mfma<<<dim3((N + 127) / 128, 2), 256, 0, stream>>>(
            bufP, Wthi + i * 65536, Wtlo + i * 65536, bm + i * 256,
            sp8 + i * 8192, bnm_g + i * 256, bnm_b + i * 256, bufQ, N);
        spmm_f16s<<<2048, 256, 0, stream>>>(bufQ, srow, sew, offsets, bufP,
                                            sp8 + (i + 1) * 8192, N);
    }

    // ---- last GCN layer (256 -> 16) ----
    bn_finalize16<<<1, 256, 0, stream>>>(sp8 + 10 * 8192, bnm_g + 10 * 256,
                                         bnm_b + 10 * 256, st, N);
    gemm16<<<(N + 15) / 16, 256, 0, stream>>>(bufP, Wl, bl, st, tmp16, N);
    spmm_small<<<(N + 15) / 16, 256, 0, stream>>>(tmp16, srow, sew, offsets, hraw, 16, N, 1);

    // ---- final BN + u/v precompute (fp16) ----
    colstats_wr<<<64, 256, 0, stream>>>(hraw, stats2 + 1 * 512, 16, N);
    bn_finalize<<<1, 256, 0, stream>>>(stats2 + 1 * 512, bno_g, bno_b, st, 16, N);
    uv_kernel<<<(N + 7) / 8, 256, 0, stream>>>(hraw, st, mW1, uvh, N);

    // ---- edge MLP (CSR order) ----
    edge_stats_csr<<<1024, 256, 0, stream>>>((const ushort*)uvh, srow, offsets, S8, N);
    mlp_finalize16<<<1, 256, 0, stream>>>(S8, mbn_g, mbn_b, ab, E);
    edge_out_csr<<<1024, 256, 0, stream>>>((const ushort*)uvh, srow, eperm, offsets,
                                           ab, mW2, mb2, outp, N);
}

// Round 5
// 1690.626 us; speedup vs baseline: 2.7400x; 1.0979x over previous
//
#include <hip/hip_runtime.h>
#include <hip/hip_bf16.h>
#include <hip/hip_fp16.h>
#include <math.h>

#define NNODES 50000
#define NEDGES 800000

// ---------------- workspace layout (bytes, 1024-aligned) ----------------
#define OFF_COUNTS   0ull                      // int[50000]  (= din)
#define OFF_DOUT     200704ull                 // int[50000]
#define OFF_CURSOR   401408ull                 // int[50000]
#define OFF_WIN      602112ull                 // float[50000]
#define OFF_STATS2   802816ull                 // float[2*512] (x stats, hraw stats)
#define OFF_SP8      806912ull                 // float[11*16*512] node-stat partials
#define OFF_MOM      1167360ull                // float[16*800] moment partials
#define ZERO_END     1218560ull
#define OFF_ST       1218560ull                // float[512]
#define OFF_ABW      1220608ull                // float[1536]  aa|bb|ww
#define OFF_OFFSETS  1226752ull                // int[50001]
#define OFF_SROW     1427456ull                // int[800000]
#define OFF_SEW      4627456ull                // float[800000]
#define OFF_TMP16    7827456ull                // float[50000*16]
#define OFF_HRAW     11027456ull               // float[50000*16]
#define OFF_WT       14227456ull               // ushort[10*256*256] fp16 W (transposed)
#define OFF_WP       15538176ull               // ushort[512*32] edge-MLP W'
#define OFF_Z        15570944ull               // ushort[50000*16] fp16 z
#define OFF_AGGZ     17172480ull               // float[50000*16]
#define OFF_BUFQ     20372480ull               // half[50000*256]
#define OFF_BUFP     45972480ull               // half[50000*256]

typedef __attribute__((ext_vector_type(8))) _Float16 f16x8;
typedef __attribute__((ext_vector_type(4))) float f32x4;

union H4 { ushort4 u; __half h[4]; };
union HU { ushort u; __half h; };

static __device__ inline ushort f2h(float f) {
    HU cv; cv.h = __float2half(f); return cv.u;
}
static __device__ inline float h2f(ushort u) {
    HU cv; cv.u = u; return __half2float(cv.h);
}

// ---------------- preprocessing ----------------

__global__ void hist_kernel(const int* __restrict__ ei, const float* __restrict__ ew,
                            int* __restrict__ counts, int* __restrict__ dout,
                            float* __restrict__ w_in, int E) {
    for (int i = blockIdx.x * blockDim.x + threadIdx.x; i < E; i += gridDim.x * blockDim.x) {
        int r = ei[i];
        int c = ei[E + i];
        atomicAdd(&counts[c], 1);
        atomicAdd(&dout[r], 1);
        atomicAdd(&w_in[c], ew[i]);
    }
}

__global__ void scan_kernel(const int* __restrict__ counts, int* __restrict__ offsets, int N) {
    __shared__ int wsum[16];
    __shared__ int carry_s;
    int tid = threadIdx.x;
    int lane = tid & 63, w = tid >> 6;
    if (tid == 0) carry_s = 0;
    __syncthreads();
    for (int base = 0; base < N; base += 1024) {
        int v = (base + tid < N) ? counts[base + tid] : 0;
        int x = v;
#pragma unroll
        for (int off = 1; off < 64; off <<= 1) {
            int y = __shfl_up(x, off);
            if (lane >= off) x += y;
        }
        if (lane == 63) wsum[w] = x;
        __syncthreads();
        if (w == 0 && lane < 16) {
            int s = wsum[lane];
#pragma unroll
            for (int off = 1; off < 16; off <<= 1) {
                int y = __shfl_up(s, off);
                if (lane >= off) s += y;
            }
            wsum[lane] = s;
        }
        __syncthreads();
        int wbase = (w > 0) ? wsum[w - 1] : 0;
        int incl = carry_s + wbase + x;
        if (base + tid < N) offsets[base + tid] = incl - v;
        __syncthreads();
        if (tid == 0) carry_s += wsum[15];
        __syncthreads();
    }
    if (tid == 0) offsets[N] = carry_s;
}

__global__ void scatter_kernel(const int* __restrict__ ei, const float* __restrict__ ew,
                               const int* __restrict__ offsets, int* __restrict__ cursor,
                               int* __restrict__ srow, float* __restrict__ sew, int E) {
    for (int i = blockIdx.x * blockDim.x + threadIdx.x; i < E; i += gridDim.x * blockDim.x) {
        int c = ei[E + i];
        int p = offsets[c] + atomicAdd(&cursor[c], 1);
        srow[p] = ei[i];
        sew[p] = ew[i];
    }
}

// ---------------- weight preconvert: Wt[n][k] = fp16(Wm[k][n]) ----------------

__global__ __launch_bounds__(256) void wconv(const float* __restrict__ Wm,
                                             ushort* __restrict__ Wt) {
    __shared__ float tile[32][33];
    int b = blockIdx.x;
    int layer = b >> 6, t = b & 63;
    int tk = (t >> 3) << 5, tn = (t & 7) << 5;
    int tid = threadIdx.x;
    int r = tid >> 5, c = tid & 31;
    const float* W = Wm + layer * 65536;
#pragma unroll
    for (int i = 0; i < 4; i++) tile[r + i * 8][c] = W[(tk + r + i * 8) * 256 + tn + c];
    __syncthreads();
#pragma unroll
    for (int i = 0; i < 4; i++) {
        int n = tn + r + i * 8, k = tk + c;
        Wt[layer * 65536 + n * 256 + k] = f2h(tile[c][r + i * 8]);
    }
}

// edge-MLP weights: Wp[n][k], n<256 branch1, n>=256 branch2 (halves swapped)
__global__ void wprep(const float* __restrict__ mW1, ushort* __restrict__ Wp) {
    int tid = threadIdx.x;
    for (int n = tid; n < 512; n += 256) {
        for (int k = 0; k < 32; k++) {
            float v;
            if (n < 256) v = mW1[k * 256 + n];
            else {
                int n2 = n - 256;
                v = (k < 16) ? mW1[(16 + k) * 256 + n2] : mW1[(k - 16) * 256 + n2];
            }
            Wp[n * 32 + k] = f2h(v);
        }
    }
}

// ---------------- small-C column stats (wave-reduced) ----------------

__global__ __launch_bounds__(256) void colstats_wr(const float* __restrict__ h,
                                                   float* __restrict__ sums, int C, int M) {
    int gtid = blockIdx.x * blockDim.x + threadIdx.x;
    int lane = threadIdx.x & 63;
    int c = gtid % C;
    int r = gtid / C;
    int stride = (gridDim.x * blockDim.x) / C;
    float s = 0.f, q = 0.f;
    for (; r < M; r += stride) {
        float v = h[r * C + c];
        s += v; q += v * v;
    }
    for (int m = 32; m >= C; m >>= 1) {
        s += __shfl_xor(s, m);
        q += __shfl_xor(q, m);
    }
    if (lane < C) {
        atomicAdd(&sums[c], s);
        atomicAdd(&sums[C + c], q);
    }
}

__global__ void bn_finalize(const float* __restrict__ sums, const float* __restrict__ g,
                            const float* __restrict__ b, float* __restrict__ st, int C, int M) {
    int c = threadIdx.x;
    if (c >= C) return;
    float mean = sums[c] / (float)M;
    float var  = sums[C + c] / (float)M - mean * mean;
    float sc = g[c] * rsqrtf(var + 1e-5f);
    st[c] = sc;
    st[C + c] = b[c] - mean * sc;
}

__global__ void bn_finalize16(const float* __restrict__ sp, const float* __restrict__ g,
                              const float* __restrict__ b, float* __restrict__ st, int M) {
    int c = threadIdx.x;
    float s = 0.f, q = 0.f;
#pragma unroll
    for (int p = 0; p < 16; p++) { s += sp[p * 512 + c]; q += sp[p * 512 + 256 + c]; }
    float mean = s / (float)M;
    float var  = q / (float)M - mean * mean;
    float sc = g[c] * rsqrtf(var + 1e-5f);
    st[c] = sc;
    st[256 + c] = b[c] - mean * sc;
}

// ---------------- MFMA GEMM (fp16): out_f16 = bn(H_f16)@W + bias ----------------

__global__ __launch_bounds__(256) void gemm_mfma(const __half* __restrict__ H,
                                                 const ushort* __restrict__ Wt,
                                                 const float* __restrict__ bias,
                                                 const float* __restrict__ sp,
                                                 const float* __restrict__ g,
                                                 const float* __restrict__ b,
                                                 __half* __restrict__ out, int M) {
    __shared__ __attribute__((aligned(16))) ushort Ah[128][40];
    __shared__ __attribute__((aligned(16))) ushort Bh[128][40];
    __shared__ __attribute__((aligned(16))) float st_s[512];
    int tid = threadIdx.x;
    int wid = tid >> 6, lane = tid & 63;
    int m0 = blockIdx.x * 128;
    int n0 = blockIdx.y * 128;
    const ushort* Hu = (const ushort*)H;

    // fused 16-partial reduce + bn_finalize
    {
        float s = 0.f, q = 0.f;
#pragma unroll
        for (int p = 0; p < 16; p++) { s += sp[p * 512 + tid]; q += sp[p * 512 + 256 + tid]; }
        float invM = 1.f / (float)M;
        float mean = s * invM;
        float var  = q * invM - mean * mean;
        float sc = g[tid] * rsqrtf(var + 1e-5f);
        st_s[tid] = sc;
        st_s[256 + tid] = b[tid] - mean * sc;
    }
    __syncthreads();

    f32x4 acc[2][8];
#pragma unroll
    for (int m = 0; m < 2; m++)
#pragma unroll
        for (int n = 0; n < 8; n++) acc[m][n] = (f32x4){0.f, 0.f, 0.f, 0.f};

    int sr = tid >> 3;
    int kq = (tid & 7) << 2;
    int fr = lane & 15;
    int qo = (lane >> 4) << 3;
    int mrow = wid << 5;

    for (int k0 = 0; k0 < 256; k0 += 32) {
#pragma unroll
        for (int t = 0; t < 4; t++) {
            int r = sr + t * 32;
            int gr = m0 + r; if (gr >= M) gr = M - 1;
            H4 h4; h4.u = *(const ushort4*)(Hu + gr * 256 + k0 + kq);
            float4 s4 = *(const float4*)(st_s + k0 + kq);
            float4 t4 = *(const float4*)(st_s + 256 + k0 + kq);
            ushort4 vh;
            vh.x = f2h(__half2float(h4.h[0]) * s4.x + t4.x);
            vh.y = f2h(__half2float(h4.h[1]) * s4.y + t4.y);
            vh.z = f2h(__half2float(h4.h[2]) * s4.z + t4.z);
            vh.w = f2h(__half2float(h4.h[3]) * s4.w + t4.w);
            *(ushort4*)&Ah[r][kq] = vh;
            ushort4 bh = *(const ushort4*)(Wt + (n0 + r) * 256 + k0 + kq);
            *(ushort4*)&Bh[r][kq] = bh;
        }
        __syncthreads();

        f16x8 a0 = *(const f16x8*)&Ah[mrow + fr][qo];
        f16x8 a1 = *(const f16x8*)&Ah[mrow + 16 + fr][qo];
#pragma unroll
        for (int nt = 0; nt < 8; nt++) {
            f16x8 bb = *(const f16x8*)&Bh[nt * 16 + fr][qo];
            acc[0][nt] = __builtin_amdgcn_mfma_f32_16x16x32_f16(a0, bb, acc[0][nt], 0, 0, 0);
            acc[1][nt] = __builtin_amdgcn_mfma_f32_16x16x32_f16(a1, bb, acc[1][nt], 0, 0, 0);
        }
        __syncthreads();
    }

#pragma unroll
    for (int mt = 0; mt < 2; mt++) {
        int gmb = m0 + mrow + mt * 16 + ((lane >> 4) << 2);
#pragma unroll
        for (int nt = 0; nt < 8; nt++) {
            int gn = n0 + nt * 16 + fr;
            float bv = bias[gn];
#pragma unroll
            for (int j = 0; j < 4; j++) {
                int gm = gmb + j;
                if (gm < M) out[gm * 256 + gn] = __float2half(acc[mt][nt][j] + bv);
            }
        }
    }
}

// ---------------- SpMM fp16 gather + fused column stats ----------------

__global__ __launch_bounds__(256) void spmm_f16s(const __half* __restrict__ T,
                                                 const int* __restrict__ srow,
                                                 const float* __restrict__ sew,
                                                 const int* __restrict__ off,
                                                 __half* __restrict__ outp,
                                                 float* __restrict__ sp, int N) {
    __shared__ float red[4][512];
    int tid = threadIdx.x;
    int wid = tid >> 6, lane = tid & 63;
    int l4 = lane << 2;
    int gw = blockIdx.x * 4 + wid, nw = gridDim.x * 4;
    const ushort* Tu = (const ushort*)T;
    ushort* Ou = (ushort*)outp;
    float cs[4] = {0, 0, 0, 0}, cq[4] = {0, 0, 0, 0};
    for (int n = gw; n < N; n += nw) {
        int e0 = off[n], e1 = off[n + 1];
        float4 acc = {0.f, 0.f, 0.f, 0.f};
        int e = e0;
        for (; e + 7 < e1; e += 8) {
            int r[8]; float w[8]; H4 v[8];
#pragma unroll
            for (int i = 0; i < 8; i++) { r[i] = srow[e + i]; w[i] = sew[e + i]; }
#pragma unroll
            for (int i = 0; i < 8; i++) v[i].u = *(const ushort4*)(Tu + r[i] * 256 + l4);
#pragma unroll
            for (int i = 0; i < 8; i++) {
                acc.x += w[i] * __half2float(v[i].h[0]);
                acc.y += w[i] * __half2float(v[i].h[1]);
                acc.z += w[i] * __half2float(v[i].h[2]);
                acc.w += w[i] * __half2float(v[i].h[3]);
            }
        }
        for (; e < e1; ++e) {
            int rr = srow[e]; float w = sew[e];
            H4 v; v.u = *(const ushort4*)(Tu + rr * 256 + l4);
            acc.x += w * __half2float(v.h[0]);
            acc.y += w * __half2float(v.h[1]);
            acc.z += w * __half2float(v.h[2]);
            acc.w += w * __half2float(v.h[3]);
        }
        acc.x = fmaxf(acc.x, 0.f); acc.y = fmaxf(acc.y, 0.f);
        acc.z = fmaxf(acc.z, 0.f); acc.w = fmaxf(acc.w, 0.f);
        H4 o;
        o.h[0] = __float2half(acc.x); o.h[1] = __float2half(acc.y);
        o.h[2] = __float2half(acc.z); o.h[3] = __float2half(acc.w);
        *(ushort4*)(Ou + n * 256 + l4) = o.u;
        cs[0] += acc.x; cq[0] += acc.x * acc.x;
        cs[1] += acc.y; cq[1] += acc.y * acc.y;
        cs[2] += acc.z; cq[2] += acc.z * acc.z;
        cs[3] += acc.w; cq[3] += acc.w * acc.w;
    }
#pragma unroll
    for (int j = 0; j < 4; j++) {
        red[wid][l4 + j] = cs[j];
        red[wid][256 + l4 + j] = cq[j];
    }
    __syncthreads();
    float* dst = sp + (blockIdx.x & 15) * 512;
    for (int i = tid; i < 512; i += 256)
        atomicAdd(&dst[i], red[0][i] + red[1][i] + red[2][i] + red[3][i]);
}

__global__ __launch_bounds__(256) void spmm_small(const float* __restrict__ T,
                                                  const int* __restrict__ srow,
                                                  const float* __restrict__ sew,
                                                  const int* __restrict__ off,
                                                  float* __restrict__ out,
                                                  int C, int N, int relu) {
    int npb = blockDim.x / C;
    int local = threadIdx.x / C;
    int c = threadIdx.x % C;
    int n = blockIdx.x * npb + local;
    if (n >= N) return;
    int e0 = off[n], e1 = off[n + 1];
    float acc = 0.f;
    for (int e = e0; e < e1; ++e) acc += sew[e] * T[srow[e] * C + c];
    if (relu) acc = fmaxf(acc, 0.f);
    out[n * C + c] = acc;
}

// ---------------- layer 0 finalize + fused column stats ----------------

__global__ __launch_bounds__(256) void layer0_fin(const float* __restrict__ agg2,
                                                  const float* __restrict__ w_in,
                                                  const float* __restrict__ st,
                                                  const float* __restrict__ W0,
                                                  const float* __restrict__ b0,
                                                  __half* __restrict__ h,
                                                  float* __restrict__ sp, int N) {
    int j = threadIdx.x;
    float w0j = W0[j], w1j = W0[256 + j], b0j = b0[j];
    float s0 = st[0], s1 = st[1], t0 = st[2], t1 = st[3];
    float cs = 0.f, cq = 0.f;
    for (int n = blockIdx.x; n < N; n += gridDim.x) {
        float wi = w_in[n];
        float a0 = agg2[n * 2 + 0] * s0 + wi * t0;
        float a1 = agg2[n * 2 + 1] * s1 + wi * t1;
        float v = fmaxf(a0 * w0j + a1 * w1j + wi * b0j, 0.f);
        h[n * 256 + j] = __float2half(v);
        cs += v; cq += v * v;
    }
    float* dst = sp + (blockIdx.x & 15) * 512;
    atomicAdd(&dst[j], cs);
    atomicAdd(&dst[256 + j], cq);
}

// ---------------- last GCN linear: [M,256]f16 x [256,16] ----------------

__global__ __launch_bounds__(256) void gemm16(const __half* __restrict__ H,
                                              const float* __restrict__ Wl,
                                              const float* __restrict__ bl,
                                              const float* __restrict__ st,
                                              float* __restrict__ out, int M) {
    __shared__ float Hs[16][256];
    __shared__ float Ws[256][16];
    int tid = threadIdx.x;
    int n0 = blockIdx.x << 4;
    const ushort* Hu = (const ushort*)H;
    for (int i = tid; i < 4096; i += 256) Ws[i >> 4][i & 15] = Wl[i];
    for (int i = tid; i < 4096; i += 256) {
        int r = i >> 8, k = i & 255;
        int n = n0 + r;
        float hv = 0.f;
        if (n < M) hv = h2f(Hu[n * 256 + k]) * st[k] + st[256 + k];
        Hs[r][k] = hv;
    }
    __syncthreads();
    int r = tid >> 4, j = tid & 15;
    float acc = bl[j];
    for (int k = 0; k < 256; k++) acc += Hs[r][k] * Ws[k][j];
    if (n0 + r < M) out[(n0 + r) * 16 + j] = acc;
}

// ---------------- z prep: z = fp16(bn(hraw)) ----------------

__global__ void zprep(const float* __restrict__ hraw, const float* __restrict__ st,
                      ushort* __restrict__ Z, int NE) {
    int i = blockIdx.x * blockDim.x + threadIdx.x;
    if (i >= NE) return;
    int c = i & 15;
    Z[i] = f2h(hraw[i] * st[c] + st[16 + c]);
}

// ---------------- unweighted 16-wide spmm: aggz[n] = sum_{e into n} z[row(e)] ----------------

__global__ __launch_bounds__(256) void aggz_spmm(const ushort* __restrict__ Z,
                                                 const int* __restrict__ srow,
                                                 const int* __restrict__ off,
                                                 float* __restrict__ aggz, int N) {
    int local = threadIdx.x >> 4;
    int c = threadIdx.x & 15;
    int n = blockIdx.x * 16 + local;
    if (n >= N) return;
    int e0 = off[n], e1 = off[n + 1];
    float acc = 0.f;
    for (int e = e0; e < e1; ++e) acc += h2f(Z[srow[e] * 16 + c]);
    aggz[n * 16 + c] = acc;
}

// ---------------- node moments: P, R, M, Sdout, Sdin ----------------

__global__ __launch_bounds__(256) void zmom(const ushort* __restrict__ Z,
                                            const float* __restrict__ aggz,
                                            const int* __restrict__ dout,
                                            const int* __restrict__ din,
                                            float* __restrict__ MOM, int N) {
    __shared__ float zs[128][17];
    __shared__ float az[128][17];
    __shared__ float dw[128][2];
    int tid = threadIdx.x;
    int i = tid >> 4, j = tid & 15;
    float p = 0.f, r = 0.f, m = 0.f, sdo = 0.f, sdi = 0.f;
    for (int base = blockIdx.x * 128; base < N; base += gridDim.x * 128) {
        int cnt = N - base; if (cnt > 128) cnt = 128;
        for (int t = tid; t < 2048; t += 256) {
            int n = t >> 4, c = t & 15;
            if (n < cnt) {
                zs[n][c] = h2f(Z[(base + n) * 16 + c]);
                az[n][c] = aggz[(base + n) * 16 + c];
            } else { zs[n][c] = 0.f; az[n][c] = 0.f; }
        }
        for (int t = tid; t < 128; t += 256) {
            if (t < cnt) { dw[t][0] = (float)dout[base + t]; dw[t][1] = (float)din[base + t]; }
            else { dw[t][0] = 0.f; dw[t][1] = 0.f; }
        }
        __syncthreads();
        for (int n = 0; n < 128; n++) {
            float zi = zs[n][i], zj = zs[n][j];
            float d0 = dw[n][0], d1 = dw[n][1];
            float zz = zi * zj;
            p += d0 * zz;
            r += d1 * zz;
            m += az[n][i] * zj;
            if (i == 0) { sdo += d0 * zj; sdi += d1 * zj; }
        }
        __syncthreads();
    }
    float* dst = MOM + (blockIdx.x & 15) * 800;
    atomicAdd(&dst[tid], p);
    atomicAdd(&dst[256 + tid], r);
    atomicAdd(&dst[512 + tid], m);
    if (i == 0) { atomicAdd(&dst[768 + j], sdo); atomicAdd(&dst[784 + j], sdi); }
}

// ---------------- analytic edge-MLP BN affine ----------------

__global__ __launch_bounds__(256) void mlp_ab(const float* __restrict__ MOM,
                                              const float* __restrict__ mW1,
                                              const float* __restrict__ g,
                                              const float* __restrict__ b,
                                              const float* __restrict__ mW2,
                                              float* __restrict__ abw, int E) {
    __shared__ float P[256], R[256], Mm[256], Sdo[16], Sdi[16];
    int tid = threadIdx.x;
    float sp = 0.f, sr = 0.f, sm = 0.f;
#pragma unroll
    for (int q = 0; q < 16; q++) {
        sp += MOM[q * 800 + tid];
        sr += MOM[q * 800 + 256 + tid];
        sm += MOM[q * 800 + 512 + tid];
    }
    P[tid] = sp; R[tid] = sr; Mm[tid] = sm;
    if (tid < 16) {
        float a = 0.f, c = 0.f;
#pragma unroll
        for (int q = 0; q < 16; q++) { a += MOM[q * 800 + 768 + tid]; c += MOM[q * 800 + 784 + tid]; }
        Sdo[tid] = a; Sdi[tid] = c;
    }
    __syncthreads();
    int j = tid;
    float A[16], B[16];
#pragma unroll
    for (int k = 0; k < 16; k++) { A[k] = mW1[k * 256 + j]; B[k] = mW1[(16 + k) * 256 + j]; }
    float apa = 0.f, brb = 0.f, amb = 0.f, bpb = 0.f, ara = 0.f, bma = 0.f;
    float aso = 0.f, bso = 0.f, asi = 0.f, bsi = 0.f;
    for (int i2 = 0; i2 < 16; i2++) {
        float Ai = A[i2], Bi = B[i2];
        aso += Ai * Sdo[i2]; bso += Bi * Sdo[i2];
        asi += Ai * Sdi[i2]; bsi += Bi * Sdi[i2];
#pragma unroll
        for (int k = 0; k < 16; k++) {
            float Pik = P[i2 * 16 + k], Rik = R[i2 * 16 + k], Mik = Mm[i2 * 16 + k];
            apa += Ai * Pik * A[k]; brb += Bi * Rik * B[k]; amb += Ai * Mik * B[k];
            bpb += Bi * Pik * B[k]; ara += Ai * Rik * A[k]; bma += Bi * Mik * A[k];
        }
    }
    float invE = 1.f / (float)E;
    float mu1 = (aso + bsi) * invE;
    float mu2 = (bso + asi) * invE;
    float e21 = (apa + brb + 2.f * amb) * invE;
    float e22 = (bpb + ara + 2.f * bma) * invE;
    float v1 = e21 - mu1 * mu1;
    float v2 = e22 - mu2 * mu2;
    float a1 = g[j] * rsqrtf(v1 + 1e-5f);
    float a2 = g[j] * rsqrtf(v2 + 1e-5f);
    abw[j] = a1;                 abw[256 + j] = a2;
    abw[512 + j] = b[j] - mu1 * a1; abw[768 + j] = b[j] - mu2 * a2;
    abw[1024 + j] = mW2[j];      abw[1280 + j] = mW2[j];
}

// ---------------- edge MLP output via MFMA in z-space ----------------
// block: 256 edges, A=[256x32] (z_row||z_col), B=W' [512x32]; out = sigmoid(0.5*sum+mb2)

__global__ __launch_bounds__(256) void edge_mfma(const ushort* __restrict__ Z,
                                                 const int* __restrict__ ei,
                                                 const ushort* __restrict__ Wp,
                                                 const float* __restrict__ abw,
                                                 const float* __restrict__ mb2,
                                                 float* __restrict__ out, int E) {
    __shared__ __attribute__((aligned(16))) ushort As[256][40];
    __shared__ __attribute__((aligned(16))) ushort Bs[512][40];
    int tid = threadIdx.x;
    int wid = tid >> 6, lane = tid & 63;
    int fr = lane & 15, qo = (lane >> 4) << 3;

    // stage B (W': 16K halves)
    for (int i = tid * 4; i < 512 * 32; i += 1024) {
        int n = i >> 5, k = i & 31;
        *(ushort4*)&Bs[n][k] = *(const ushort4*)(Wp + i);
    }
    // stage A
    int e0 = blockIdx.x * 256;
    {
        int e = e0 + tid;
        int r = 0, c = 0;
        if (e < E) { r = ei[e]; c = ei[E + e]; }
        uint4 z0 = *(const uint4*)(Z + r * 16);
        uint4 z1 = *(const uint4*)(Z + r * 16 + 8);
        uint4 z2 = *(const uint4*)(Z + c * 16);
        uint4 z3 = *(const uint4*)(Z + c * 16 + 8);
        *(uint4*)&As[tid][0]  = z0; *(uint4*)&As[tid][8]  = z1;
        *(uint4*)&As[tid][16] = z2; *(uint4*)&As[tid][24] = z3;
    }
    __syncthreads();

    f16x8 a[4];
#pragma unroll
    for (int mt = 0; mt < 4; mt++) a[mt] = *(const f16x8*)&As[(wid * 4 + mt) * 16 + fr][qo];
    float pacc[4][4];
#pragma unroll
    for (int mt = 0; mt < 4; mt++)
#pragma unroll
        for (int j = 0; j < 4; j++) pacc[mt][j] = 0.f;
    float mb2v = mb2[0];

    for (int n = 0; n < 32; n++) {
        f16x8 bfr = *(const f16x8*)&Bs[n * 16 + fr][qo];
        int col = n * 16 + fr;
        float av = abw[col], bv = abw[512 + col], wv = abw[1024 + col];
#pragma unroll
        for (int mt = 0; mt < 4; mt++) {
            f32x4 c0 = {0.f, 0.f, 0.f, 0.f};
            c0 = __builtin_amdgcn_mfma_f32_16x16x32_f16(a[mt], bfr, c0, 0, 0, 0);
#pragma unroll
            for (int j = 0; j < 4; j++)
                pacc[mt][j] += fmaxf(c0[j] * av + bv, 0.f) * wv;
        }
    }

#pragma unroll
    for (int mt = 0; mt < 4; mt++)
#pragma unroll
        for (int j = 0; j < 4; j++) {
            float p = pacc[mt][j];
            p += __shfl_xor(p, 1);
            p += __shfl_xor(p, 2);
            p += __shfl_xor(p, 4);
            p += __shfl_xor(p, 8);
            if (fr == 0) {
                int row = (wid * 4 + mt) * 16 + ((lane >> 4) << 2) + j;
                int e = e0 + row;
                if (e < E) out[e] = 1.f / (1.f + expf(-(0.5f * p + mb2v)));
            }
        }
}

// ---------------- launch ----------------

extern "C" void kernel_launch(void* const* d_in, const int* in_sizes, int n_in,
                              void* d_out, int out_size, void* d_ws, size_t ws_size,
                              hipStream_t stream) {
    const float* x     = (const float*)d_in[0];
    const int*   ei    = (const int*)d_in[1];
    const float* ew    = (const float*)d_in[2];
    const float* W0    = (const float*)d_in[3];
    const float* b0    = (const float*)d_in[4];
    const float* Wm    = (const float*)d_in[5];
    const float* bm    = (const float*)d_in[6];
    const float* Wl    = (const float*)d_in[7];
    const float* bl    = (const float*)d_in[8];
    const float* bn0_g = (const float*)d_in[9];
    const float* bn0_b = (const float*)d_in[10];
    const float* bnm_g = (const float*)d_in[11];
    const float* bnm_b = (const float*)d_in[12];
    const float* bno_g = (const float*)d_in[13];
    const float* bno_b = (const float*)d_in[14];
    const float* mW1   = (const float*)d_in[15];
    const float* mbn_g = (const float*)d_in[17];
    const float* mbn_b = (const float*)d_in[18];
    const float* mW2   = (const float*)d_in[19];
    const float* mb2   = (const float*)d_in[20];
    float* outp = (float*)d_out;

    char* ws = (char*)d_ws;
    int*    counts  = (int*)(ws + OFF_COUNTS);
    int*    dout    = (int*)(ws + OFF_DOUT);
    int*    cursor  = (int*)(ws + OFF_CURSOR);
    float*  w_in    = (float*)(ws + OFF_WIN);
    float*  stats2  = (float*)(ws + OFF_STATS2);
    float*  sp8     = (float*)(ws + OFF_SP8);
    float*  MOM     = (float*)(ws + OFF_MOM);
    float*  st      = (float*)(ws + OFF_ST);
    float*  abw     = (float*)(ws + OFF_ABW);
    int*    offsets = (int*)(ws + OFF_OFFSETS);
    int*    srow    = (int*)(ws + OFF_SROW);
    float*  sew     = (float*)(ws + OFF_SEW);
    float*  tmp16   = (float*)(ws + OFF_TMP16);
    float*  hraw    = (float*)(ws + OFF_HRAW);
    ushort* Wt      = (ushort*)(ws + OFF_WT);
    ushort* Wp      = (ushort*)(ws + OFF_WP);
    ushort* Z       = (ushort*)(ws + OFF_Z);
    float*  aggz    = (float*)(ws + OFF_AGGZ);
    __half* bufQ    = (__half*)(ws + OFF_BUFQ);
    __half* bufP    = (__half*)(ws + OFF_BUFP);
    float*  agg2    = tmp16;

    const int N = NNODES, E = NEDGES;

    hipMemsetAsync(ws, 0, ZERO_END, stream);

    // CSR build + weight preconvert
    hist_kernel<<<1024, 256, 0, stream>>>(ei, ew, counts, dout, w_in, E);
    wconv<<<640, 256, 0, stream>>>(Wm, Wt);
    wprep<<<1, 256, 0, stream>>>(mW1, Wp);
    scan_kernel<<<1, 1024, 0, stream>>>(counts, offsets, N);
    scatter_kernel<<<1024, 256, 0, stream>>>(ei, ew, offsets, cursor, srow, sew, E);

    // ---- layer 0 ----
    colstats_wr<<<64, 256, 0, stream>>>(x, stats2 + 0 * 512, 2, N);
    bn_finalize<<<1, 256, 0, stream>>>(stats2 + 0 * 512, bn0_g, bn0_b, st, 2, N);
    spmm_small<<<(N + 127) / 128, 256, 0, stream>>>(x, srow, sew, offsets, agg2, 2, N, 0);
    layer0_fin<<<512, 256, 0, stream>>>(agg2, w_in, st, W0, b0, bufP, sp8 + 0 * 8192, N);

    // ---- 10 mid layers ----
    for (int i = 0; i < 10; i++) {
        gemm_mfma<<<dim3((N + 127) / 128, 2), 256, 0, stream>>>(
            bufP, Wt + i * 65536, bm + i * 256,
            sp8 + i * 8192, bnm_g + i * 256, bnm_b + i * 256, bufQ, N);
        spmm_f16s<<<2048, 256, 0, stream>>>(bufQ, srow, sew, offsets, bufP,
                                            sp8 + (i + 1) * 8192, N);
    }

    // ---- last GCN layer (256 -> 16) ----
    bn_finalize16<<<1, 256, 0, stream>>>(sp8 + 10 * 8192, bnm_g + 10 * 256,
                                         bnm_b + 10 * 256, st, N);
    gemm16<<<(N + 15) / 16, 256, 0, stream>>>(bufP, Wl, bl, st, tmp16, N);
    spmm_small<<<(N + 15) / 16, 256, 0, stream>>>(tmp16, srow, sew, offsets, hraw, 16, N, 1);

    // ---- final BN -> z (fp16) ----
    colstats_wr<<<64, 256, 0, stream>>>(hraw, stats2 + 1 * 512, 16, N);
    bn_finalize<<<1, 256, 0, stream>>>(stats2 + 1 * 512, bno_g, bno_b, st, 16, N);
    zprep<<<(N * 16 + 255) / 256, 256, 0, stream>>>(hraw, st, Z, N * 16);

    // ---- analytic edge-MLP BN stats ----
    aggz_spmm<<<(N + 15) / 16, 256, 0, stream>>>(Z, srow, offsets, aggz, N);
    zmom<<<256, 256, 0, stream>>>(Z, aggz, dout, counts, MOM, N);
    mlp_ab<<<1, 256, 0, stream>>>(MOM, mW1, mbn_g, mbn_b, mW2, abw, E);

    // ---- edge MLP output (MFMA) ----
    edge_mfma<<<(E + 255) / 256, 256, 0, stream>>>(Z, ei, Wp, abw, mb2, outp, E);
}

// Round 6
// 1544.080 us; speedup vs baseline: 3.0000x; 1.0949x over previous
//
#include <hip/hip_runtime.h>
#include <hip/hip_bf16.h>
#include <hip/hip_fp16.h>
#include <math.h>

#define NNODES 50000
#define NEDGES 800000

// ---------------- workspace layout (bytes, 1024-aligned) ----------------
#define OFF_CW       0ull                      // u64[50000] packed count|w_in (zeroed)
#define OFF_DOUT     401408ull                 // int[50000] (zeroed)
#define OFF_STATS2   602112ull                 // float[2*512] (zeroed)
#define OFF_SP8      606208ull                 // float[11*16*512] (zeroed)
#define OFF_MOM      966656ull                 // float[16*800] (zeroed)
#define ZERO_END     1017856ull
#define OFF_ST       1017856ull                // float[512]
#define OFF_ABW      1019904ull                // float[1536]
#define OFF_WIN      1026048ull                // float[50000] (written by scan)
#define OFF_OFFSETS  1226752ull                // int[50001]
#define OFF_SROW     1427456ull                // int[800000]
#define OFF_SEW      4627456ull                // float[800000]
#define OFF_RANK     7827456ull                // int[800000]
#define OFF_WT       11027456ull               // ushort[10*256*256] fp16 W (transposed)
#define OFF_WP       12338176ull               // ushort[512*32]
#define OFF_BUFQ     12371968ull               // half[50000*256]
#define OFF_BUFP     37971968ull               // half[50000*256]
// aliases inside dead BUFQ (after 10th spmm):
#define ALI_TMP16    0ull                      // float[50000*16]
#define ALI_HRAW     3276800ull                // float[50000*16]
#define ALI_Z        6553600ull                // ushort[50000*16]
#define ALI_AGGZ     8388608ull                // float[50000*16]

typedef __attribute__((ext_vector_type(8))) _Float16 f16x8;
typedef __attribute__((ext_vector_type(4))) float f32x4;

union H4 { ushort4 u; __half h[4]; };
union US8 { uint4 u; __half h[8]; };
union HU { ushort u; __half h; };

static __device__ inline ushort f2h(float f) {
    HU cv; cv.h = __float2half(f); return cv.u;
}
static __device__ inline float h2f(ushort u) {
    HU cv; cv.u = u; return __half2float(cv.h);
}

// ---------------- preprocessing ----------------
// packed cw[c]: count in bits [40..], sum(ew * 2^20) in low bits.

__global__ void hist_kernel(const int* __restrict__ ei, const float* __restrict__ ew,
                            unsigned long long* __restrict__ cw, int* __restrict__ dout,
                            int* __restrict__ rank, int E) {
    for (int i = blockIdx.x * blockDim.x + threadIdx.x; i < E; i += gridDim.x * blockDim.x) {
        int r = ei[i];
        int c = ei[E + i];
        unsigned long long pack = (1ull << 40) |
            (unsigned long long)__float2uint_rn(ew[i] * 1048576.f);
        unsigned long long old = atomicAdd(&cw[c], pack);
        rank[i] = (int)(old >> 40);
        atomicAdd(&dout[r], 1);
    }
}

__global__ void scan_kernel(const unsigned long long* __restrict__ cw,
                            int* __restrict__ offsets, float* __restrict__ w_in, int N) {
    __shared__ int wsum[16];
    __shared__ int carry_s;
    int tid = threadIdx.x;
    int lane = tid & 63, w = tid >> 6;
    if (tid == 0) carry_s = 0;
    __syncthreads();
    for (int base = 0; base < N; base += 1024) {
        int v = 0;
        if (base + tid < N) {
            unsigned long long cv = cw[base + tid];
            v = (int)(cv >> 40);
            w_in[base + tid] = (float)(cv & 0xFFFFFFFFFFull) * (1.f / 1048576.f);
        }
        int x = v;
#pragma unroll
        for (int off = 1; off < 64; off <<= 1) {
            int y = __shfl_up(x, off);
            if (lane >= off) x += y;
        }
        if (lane == 63) wsum[w] = x;
        __syncthreads();
        if (w == 0 && lane < 16) {
            int s = wsum[lane];
#pragma unroll
            for (int off = 1; off < 16; off <<= 1) {
                int y = __shfl_up(s, off);
                if (lane >= off) s += y;
            }
            wsum[lane] = s;
        }
        __syncthreads();
        int wbase = (w > 0) ? wsum[w - 1] : 0;
        int incl = carry_s + wbase + x;
        if (base + tid < N) offsets[base + tid] = incl - v;
        __syncthreads();
        if (tid == 0) carry_s += wsum[15];
        __syncthreads();
    }
    if (tid == 0) offsets[N] = carry_s;
}

__global__ void scatter_kernel(const int* __restrict__ ei, const float* __restrict__ ew,
                               const int* __restrict__ offsets, const int* __restrict__ rank,
                               int* __restrict__ srow, float* __restrict__ sew, int E) {
    for (int i = blockIdx.x * blockDim.x + threadIdx.x; i < E; i += gridDim.x * blockDim.x) {
        int c = ei[E + i];
        int p = offsets[c] + rank[i];
        srow[p] = ei[i];
        sew[p] = ew[i];
    }
}

// ---------------- weight preconvert: Wt[n][k] = fp16(Wm[k][n]) ----------------

__global__ __launch_bounds__(256) void wconv(const float* __restrict__ Wm,
                                             ushort* __restrict__ Wt) {
    __shared__ float tile[32][33];
    int b = blockIdx.x;
    int layer = b >> 6, t = b & 63;
    int tk = (t >> 3) << 5, tn = (t & 7) << 5;
    int tid = threadIdx.x;
    int r = tid >> 5, c = tid & 31;
    const float* W = Wm + layer * 65536;
#pragma unroll
    for (int i = 0; i < 4; i++) tile[r + i * 8][c] = W[(tk + r + i * 8) * 256 + tn + c];
    __syncthreads();
#pragma unroll
    for (int i = 0; i < 4; i++) {
        int n = tn + r + i * 8, k = tk + c;
        Wt[layer * 65536 + n * 256 + k] = f2h(tile[c][r + i * 8]);
    }
}

__global__ void wprep(const float* __restrict__ mW1, ushort* __restrict__ Wp) {
    int tid = threadIdx.x;
    for (int n = tid; n < 512; n += 256) {
        for (int k = 0; k < 32; k++) {
            float v;
            if (n < 256) v = mW1[k * 256 + n];
            else {
                int n2 = n - 256;
                v = (k < 16) ? mW1[(16 + k) * 256 + n2] : mW1[(k - 16) * 256 + n2];
            }
            Wp[n * 32 + k] = f2h(v);
        }
    }
}

// ---------------- small-C column stats (wave-reduced) ----------------

__global__ __launch_bounds__(256) void colstats_wr(const float* __restrict__ h,
                                                   float* __restrict__ sums, int C, int M) {
    int gtid = blockIdx.x * blockDim.x + threadIdx.x;
    int lane = threadIdx.x & 63;
    int c = gtid % C;
    int r = gtid / C;
    int stride = (gridDim.x * blockDim.x) / C;
    float s = 0.f, q = 0.f;
    for (; r < M; r += stride) {
        float v = h[r * C + c];
        s += v; q += v * v;
    }
    for (int m = 32; m >= C; m >>= 1) {
        s += __shfl_xor(s, m);
        q += __shfl_xor(q, m);
    }
    if (lane < C) {
        atomicAdd(&sums[c], s);
        atomicAdd(&sums[C + c], q);
    }
}

__global__ void bn_finalize(const float* __restrict__ sums, const float* __restrict__ g,
                            const float* __restrict__ b, float* __restrict__ st, int C, int M) {
    int c = threadIdx.x;
    if (c >= C) return;
    float mean = sums[c] / (float)M;
    float var  = sums[C + c] / (float)M - mean * mean;
    float sc = g[c] * rsqrtf(var + 1e-5f);
    st[c] = sc;
    st[C + c] = b[c] - mean * sc;
}

__global__ void bn_finalize16(const float* __restrict__ sp, const float* __restrict__ g,
                              const float* __restrict__ b, float* __restrict__ st, int M) {
    int c = threadIdx.x;
    float s = 0.f, q = 0.f;
#pragma unroll
    for (int p = 0; p < 16; p++) { s += sp[p * 512 + c]; q += sp[p * 512 + 256 + c]; }
    float mean = s / (float)M;
    float var  = q / (float)M - mean * mean;
    float sc = g[c] * rsqrtf(var + 1e-5f);
    st[c] = sc;
    st[256 + c] = b[c] - mean * sc;
}

// ---------------- MFMA GEMM (fp16): out_f16 = bn(H_f16)@W + bias ----------------

__global__ __launch_bounds__(256) void gemm_mfma(const __half* __restrict__ H,
                                                 const ushort* __restrict__ Wt,
                                                 const float* __restrict__ bias,
                                                 const float* __restrict__ sp,
                                                 const float* __restrict__ g,
                                                 const float* __restrict__ b,
                                                 __half* __restrict__ out, int M) {
    __shared__ __attribute__((aligned(16))) ushort Ah[128][40];
    __shared__ __attribute__((aligned(16))) ushort Bh[128][40];
    __shared__ __attribute__((aligned(16))) float st_s[512];
    int tid = threadIdx.x;
    int wid = tid >> 6, lane = tid & 63;
    int m0 = blockIdx.x * 128;
    int n0 = blockIdx.y * 128;
    const ushort* Hu = (const ushort*)H;

    {
        float s = 0.f, q = 0.f;
#pragma unroll
        for (int p = 0; p < 16; p++) { s += sp[p * 512 + tid]; q += sp[p * 512 + 256 + tid]; }
        float invM = 1.f / (float)M;
        float mean = s * invM;
        float var  = q * invM - mean * mean;
        float sc = g[tid] * rsqrtf(var + 1e-5f);
        st_s[tid] = sc;
        st_s[256 + tid] = b[tid] - mean * sc;
    }
    __syncthreads();

    f32x4 acc[2][8];
#pragma unroll
    for (int m = 0; m < 2; m++)
#pragma unroll
        for (int n = 0; n < 8; n++) acc[m][n] = (f32x4){0.f, 0.f, 0.f, 0.f};

    int sr = tid >> 3;
    int kq = (tid & 7) << 2;
    int fr = lane & 15;
    int qo = (lane >> 4) << 3;
    int mrow = wid << 5;

    for (int k0 = 0; k0 < 256; k0 += 32) {
#pragma unroll
        for (int t = 0; t < 4; t++) {
            int r = sr + t * 32;
            int gr = m0 + r; if (gr >= M) gr = M - 1;
            H4 h4; h4.u = *(const ushort4*)(Hu + gr * 256 + k0 + kq);
            float4 s4 = *(const float4*)(st_s + k0 + kq);
            float4 t4 = *(const float4*)(st_s + 256 + k0 + kq);
            ushort4 vh;
            vh.x = f2h(__half2float(h4.h[0]) * s4.x + t4.x);
            vh.y = f2h(__half2float(h4.h[1]) * s4.y + t4.y);
            vh.z = f2h(__half2float(h4.h[2]) * s4.z + t4.z);
            vh.w = f2h(__half2float(h4.h[3]) * s4.w + t4.w);
            *(ushort4*)&Ah[r][kq] = vh;
            ushort4 bh = *(const ushort4*)(Wt + (n0 + r) * 256 + k0 + kq);
            *(ushort4*)&Bh[r][kq] = bh;
        }
        __syncthreads();

        f16x8 a0 = *(const f16x8*)&Ah[mrow + fr][qo];
        f16x8 a1 = *(const f16x8*)&Ah[mrow + 16 + fr][qo];
#pragma unroll
        for (int nt = 0; nt < 8; nt++) {
            f16x8 bb = *(const f16x8*)&Bh[nt * 16 + fr][qo];
            acc[0][nt] = __builtin_amdgcn_mfma_f32_16x16x32_f16(a0, bb, acc[0][nt], 0, 0, 0);
            acc[1][nt] = __builtin_amdgcn_mfma_f32_16x16x32_f16(a1, bb, acc[1][nt], 0, 0, 0);
        }
        __syncthreads();
    }

#pragma unroll
    for (int mt = 0; mt < 2; mt++) {
        int gmb = m0 + mrow + mt * 16 + ((lane >> 4) << 2);
#pragma unroll
        for (int nt = 0; nt < 8; nt++) {
            int gn = n0 + nt * 16 + fr;
            float bv = bias[gn];
#pragma unroll
            for (int j = 0; j < 4; j++) {
                int gm = gmb + j;
                if (gm < M) out[gm * 256 + gn] = __float2half(acc[mt][nt][j] + bv);
            }
        }
    }
}

// ---------------- SpMM fp16: 2 edges/wave, 16B loads, fused column stats ----------------

__global__ __launch_bounds__(256) void spmm_f16w(const __half* __restrict__ T,
                                                 const int* __restrict__ srow,
                                                 const float* __restrict__ sew,
                                                 const int* __restrict__ off,
                                                 __half* __restrict__ outp,
                                                 float* __restrict__ sp, int N) {
    __shared__ float red[4][512];
    int tid = threadIdx.x;
    int wid = tid >> 6, lane = tid & 63;
    int hh = lane >> 5;           // half-wave index
    int li = lane & 31;
    int colb = li << 3;           // column base (8 cols per lane)
    const ushort* Tu = (const ushort*)T;
    ushort* Ou = (ushort*)outp;
    float cs[8] = {0, 0, 0, 0, 0, 0, 0, 0}, cq[8] = {0, 0, 0, 0, 0, 0, 0, 0};
    int gw = blockIdx.x * 4 + wid, nw = gridDim.x * 4;
    for (int n = gw; n < N; n += nw) {
        int e0 = off[n], e1 = off[n + 1];
        float acc[8] = {0, 0, 0, 0, 0, 0, 0, 0};
        int e = e0;
        for (; e + 7 < e1; e += 8) {
            int rr[4]; float wv[4]; US8 v[4];
#pragma unroll
            for (int i = 0; i < 4; i++) { rr[i] = srow[e + 2 * i + hh]; wv[i] = sew[e + 2 * i + hh]; }
#pragma unroll
            for (int i = 0; i < 4; i++) v[i].u = *(const uint4*)(Tu + rr[i] * 256 + colb);
#pragma unroll
            for (int i = 0; i < 4; i++)
#pragma unroll
                for (int j = 0; j < 8; j++) acc[j] += wv[i] * __half2float(v[i].h[j]);
        }
        for (; e < e1; e += 2) {
            if (e + hh < e1) {
                int r = srow[e + hh]; float w = sew[e + hh];
                US8 v; v.u = *(const uint4*)(Tu + r * 256 + colb);
#pragma unroll
                for (int j = 0; j < 8; j++) acc[j] += w * __half2float(v.h[j]);
            }
        }
        US8 o;
#pragma unroll
        for (int j = 0; j < 8; j++) {
            float other = __shfl(acc[j], lane ^ 32, 64);
            float s = fmaxf(acc[j] + other, 0.f);
            o.h[j] = __float2half(s);
            if (hh == 0) { cs[j] += s; cq[j] += s * s; }
        }
        if (hh == 0) *(uint4*)(Ou + n * 256 + colb) = o.u;
    }
    if (hh == 0) {
#pragma unroll
        for (int j = 0; j < 8; j++) {
            red[wid][colb + j] = cs[j];
            red[wid][256 + colb + j] = cq[j];
        }
    }
    __syncthreads();
    float* dst = sp + (blockIdx.x & 15) * 512;
    for (int i = tid; i < 512; i += 256)
        atomicAdd(&dst[i], red[0][i] + red[1][i] + red[2][i] + red[3][i]);
}

__global__ __launch_bounds__(256) void spmm_small(const float* __restrict__ T,
                                                  const int* __restrict__ srow,
                                                  const float* __restrict__ sew,
                                                  const int* __restrict__ off,
                                                  float* __restrict__ out,
                                                  int C, int N, int relu) {
    int npb = blockDim.x / C;
    int local = threadIdx.x / C;
    int c = threadIdx.x % C;
    int n = blockIdx.x * npb + local;
    if (n >= N) return;
    int e0 = off[n], e1 = off[n + 1];
    float acc = 0.f;
    for (int e = e0; e < e1; ++e) acc += sew[e] * T[srow[e] * C + c];
    if (relu) acc = fmaxf(acc, 0.f);
    out[n * C + c] = acc;
}

// ---------------- layer 0 finalize + fused column stats ----------------

__global__ __launch_bounds__(256) void layer0_fin(const float* __restrict__ agg2,
                                                  const float* __restrict__ w_in,
                                                  const float* __restrict__ st,
                                                  const float* __restrict__ W0,
                                                  const float* __restrict__ b0,
                                                  __half* __restrict__ h,
                                                  float* __restrict__ sp, int N) {
    int j = threadIdx.x;
    float w0j = W0[j], w1j = W0[256 + j], b0j = b0[j];
    float s0 = st[0], s1 = st[1], t0 = st[2], t1 = st[3];
    float cs = 0.f, cq = 0.f;
    for (int n = blockIdx.x; n < N; n += gridDim.x) {
        float wi = w_in[n];
        float a0 = agg2[n * 2 + 0] * s0 + wi * t0;
        float a1 = agg2[n * 2 + 1] * s1 + wi * t1;
        float v = fmaxf(a0 * w0j + a1 * w1j + wi * b0j, 0.f);
        h[n * 256 + j] = __float2half(v);
        cs += v; cq += v * v;
    }
    float* dst = sp + (blockIdx.x & 15) * 512;
    atomicAdd(&dst[j], cs);
    atomicAdd(&dst[256 + j], cq);
}

// ---------------- last GCN linear: [M,256]f16 x [256,16] ----------------

__global__ __launch_bounds__(256) void gemm16(const __half* __restrict__ H,
                                              const float* __restrict__ Wl,
                                              const float* __restrict__ bl,
                                              const float* __restrict__ st,
                                              float* __restrict__ out, int M) {
    __shared__ float Hs[16][256];
    __shared__ float Ws[256][16];
    int tid = threadIdx.x;
    int n0 = blockIdx.x << 4;
    const ushort* Hu = (const ushort*)H;
    for (int i = tid; i < 4096; i += 256) Ws[i >> 4][i & 15] = Wl[i];
    for (int i = tid; i < 4096; i += 256) {
        int r = i >> 8, k = i & 255;
        int n = n0 + r;
        float hv = 0.f;
        if (n < M) hv = h2f(Hu[n * 256 + k]) * st[k] + st[256 + k];
        Hs[r][k] = hv;
    }
    __syncthreads();
    int r = tid >> 4, j = tid & 15;
    float acc = bl[j];
    for (int k = 0; k < 256; k++) acc += Hs[r][k] * Ws[k][j];
    if (n0 + r < M) out[(n0 + r) * 16 + j] = acc;
}

// ---------------- z prep: z = fp16(bn(hraw)) ----------------

__global__ void zprep(const float* __restrict__ hraw, const float* __restrict__ st,
                      ushort* __restrict__ Z, int NE) {
    int i = blockIdx.x * blockDim.x + threadIdx.x;
    if (i >= NE) return;
    int c = i & 15;
    Z[i] = f2h(hraw[i] * st[c] + st[16 + c]);
}

// ---------------- unweighted 16-wide spmm ----------------

__global__ __launch_bounds__(256) void aggz_spmm(const ushort* __restrict__ Z,
                                                 const int* __restrict__ srow,
                                                 const int* __restrict__ off,
                                                 float* __restrict__ aggz, int N) {
    int local = threadIdx.x >> 4;
    int c = threadIdx.x & 15;
    int n = blockIdx.x * 16 + local;
    if (n >= N) return;
    int e0 = off[n], e1 = off[n + 1];
    float acc = 0.f;
    for (int e = e0; e < e1; ++e) acc += h2f(Z[srow[e] * 16 + c]);
    aggz[n * 16 + c] = acc;
}

// ---------------- node moments: P, R, M, Sdout, Sdin ----------------

__global__ __launch_bounds__(256) void zmom(const ushort* __restrict__ Z,
                                            const float* __restrict__ aggz,
                                            const int* __restrict__ dout,
                                            const unsigned long long* __restrict__ cw,
                                            float* __restrict__ MOM, int N) {
    __shared__ float zs[128][17];
    __shared__ float az[128][17];
    __shared__ float dw[128][2];
    int tid = threadIdx.x;
    int i = tid >> 4, j = tid & 15;
    float p = 0.f, r = 0.f, m = 0.f, sdo = 0.f, sdi = 0.f;
    for (int base = blockIdx.x * 128; base < N; base += gridDim.x * 128) {
        int cnt = N - base; if (cnt > 128) cnt = 128;
        for (int t = tid; t < 2048; t += 256) {
            int n = t >> 4, c = t & 15;
            if (n < cnt) {
                zs[n][c] = h2f(Z[(base + n) * 16 + c]);
                az[n][c] = aggz[(base + n) * 16 + c];
            } else { zs[n][c] = 0.f; az[n][c] = 0.f; }
        }
        for (int t = tid; t < 128; t += 256) {
            if (t < cnt) {
                dw[t][0] = (float)dout[base + t];
                dw[t][1] = (float)(int)(cw[base + t] >> 40);
            } else { dw[t][0] = 0.f; dw[t][1] = 0.f; }
        }
        __syncthreads();
        for (int n = 0; n < 128; n++) {
            float zi = zs[n][i], zj = zs[n][j];
            float d0 = dw[n][0], d1 = dw[n][1];
            float zz = zi * zj;
            p += d0 * zz;
            r += d1 * zz;
            m += az[n][i] * zj;
            if (i == 0) { sdo += d0 * zj; sdi += d1 * zj; }
        }
        __syncthreads();
    }
    float* dst = MOM + (blockIdx.x & 15) * 800;
    atomicAdd(&dst[tid], p);
    atomicAdd(&dst[256 + tid], r);
    atomicAdd(&dst[512 + tid], m);
    if (i == 0) { atomicAdd(&dst[768 + j], sdo); atomicAdd(&dst[784 + j], sdi); }
}

// ---------------- analytic edge-MLP BN affine ----------------

__global__ __launch_bounds__(256) void mlp_ab(const float* __restrict__ MOM,
                                              const float* __restrict__ mW1,
                                              const float* __restrict__ g,
                                              const float* __restrict__ b,
                                              const float* __restrict__ mW2,
                                              float* __restrict__ abw, int E) {
    __shared__ float P[256], R[256], Mm[256], Sdo[16], Sdi[16];
    int tid = threadIdx.x;
    float sp = 0.f, sr = 0.f, sm = 0.f;
#pragma unroll
    for (int q = 0; q < 16; q++) {
        sp += MOM[q * 800 + tid];
        sr += MOM[q * 800 + 256 + tid];
        sm += MOM[q * 800 + 512 + tid];
    }
    P[tid] = sp; R[tid] = sr; Mm[tid] = sm;
    if (tid < 16) {
        float a = 0.f, c = 0.f;
#pragma unroll
        for (int q = 0; q < 16; q++) { a += MOM[q * 800 + 768 + tid]; c += MOM[q * 800 + 784 + tid]; }
        Sdo[tid] = a; Sdi[tid] = c;
    }
    __syncthreads();
    int j = tid;
    float A[16], B[16];
#pragma unroll
    for (int k = 0; k < 16; k++) { A[k] = mW1[k * 256 + j]; B[k] = mW1[(16 + k) * 256 + j]; }
    float apa = 0.f, brb = 0.f, amb = 0.f, bpb = 0.f, ara = 0.f, bma = 0.f;
    float aso = 0.f, bso = 0.f, asi = 0.f, bsi = 0.f;
    for (int i2 = 0; i2 < 16; i2++) {
        float Ai = A[i2], Bi = B[i2];
        aso += Ai * Sdo[i2]; bso += Bi * Sdo[i2];
        asi += Ai * Sdi[i2]; bsi += Bi * Sdi[i2];
#pragma unroll
        for (int k = 0; k < 16; k++) {
            float Pik = P[i2 * 16 + k], Rik = R[i2 * 16 + k], Mik = Mm[i2 * 16 + k];
            apa += Ai * Pik * A[k]; brb += Bi * Rik * B[k]; amb += Ai * Mik * B[k];
            bpb += Bi * Pik * B[k]; ara += Ai * Rik * A[k]; bma += Bi * Mik * A[k];
        }
    }
    float invE = 1.f / (float)E;
    float mu1 = (aso + bsi) * invE;
    float mu2 = (bso + asi) * invE;
    float e21 = (apa + brb + 2.f * amb) * invE;
    float e22 = (bpb + ara + 2.f * bma) * invE;
    float v1 = e21 - mu1 * mu1;
    float v2 = e22 - mu2 * mu2;
    float a1 = g[j] * rsqrtf(v1 + 1e-5f);
    float a2 = g[j] * rsqrtf(v2 + 1e-5f);
    abw[j] = a1;                 abw[256 + j] = a2;
    abw[512 + j] = b[j] - mu1 * a1; abw[768 + j] = b[j] - mu2 * a2;
    abw[1024 + j] = mW2[j];      abw[1280 + j] = mW2[j];
}

// ---------------- edge MLP output via MFMA in z-space ----------------

__global__ __launch_bounds__(256) void edge_mfma(const ushort* __restrict__ Z,
                                                 const int* __restrict__ ei,
                                                 const ushort* __restrict__ Wp,
                                                 const float* __restrict__ abw,
                                                 const float* __restrict__ mb2,
                                                 float* __restrict__ out, int E) {
    __shared__ __attribute__((aligned(16))) ushort As[256][40];
    __shared__ __attribute__((aligned(16))) ushort Bs[512][40];
    int tid = threadIdx.x;
    int wid = tid >> 6, lane = tid & 63;
    int fr = lane & 15, qo = (lane >> 4) << 3;

    for (int i = tid * 4; i < 512 * 32; i += 1024) {
        int n = i >> 5, k = i & 31;
        *(ushort4*)&Bs[n][k] = *(const ushort4*)(Wp + i);
    }
    int e0 = blockIdx.x * 256;
    {
        int e = e0 + tid;
        int r = 0, c = 0;
        if (e < E) { r = ei[e]; c = ei[E + e]; }
        uint4 z0 = *(const uint4*)(Z + r * 16);
        uint4 z1 = *(const uint4*)(Z + r * 16 + 8);
        uint4 z2 = *(const uint4*)(Z + c * 16);
        uint4 z3 = *(const uint4*)(Z + c * 16 + 8);
        *(uint4*)&As[tid][0]  = z0; *(uint4*)&As[tid][8]  = z1;
        *(uint4*)&As[tid][16] = z2; *(uint4*)&As[tid][24] = z3;
    }
    __syncthreads();

    f16x8 a[4];
#pragma unroll
    for (int mt = 0; mt < 4; mt++) a[mt] = *(const f16x8*)&As[(wid * 4 + mt) * 16 + fr][qo];
    float pacc[4][4];
#pragma unroll
    for (int mt = 0; mt < 4; mt++)
#pragma unroll
        for (int j = 0; j < 4; j++) pacc[mt][j] = 0.f;
    float mb2v = mb2[0];

    for (int n = 0; n < 32; n++) {
        f16x8 bfr = *(const f16x8*)&Bs[n * 16 + fr][qo];
        int col = n * 16 + fr;
        float av = abw[col], bv = abw[512 + col], wv = abw[1024 + col];
#pragma unroll
        for (int mt = 0; mt < 4; mt++) {
            f32x4 c0 = {0.f, 0.f, 0.f, 0.f};
            c0 = __builtin_amdgcn_mfma_f32_16x16x32_f16(a[mt], bfr, c0, 0, 0, 0);
#pragma unroll
            for (int j = 0; j < 4; j++)
                pacc[mt][j] += fmaxf(c0[j] * av + bv, 0.f) * wv;
        }
    }

#pragma unroll
    for (int mt = 0; mt < 4; mt++)
#pragma unroll
        for (int j = 0; j < 4; j++) {
            float p = pacc[mt][j];
            p += __shfl_xor(p, 1);
            p += __shfl_xor(p, 2);
            p += __shfl_xor(p, 4);
            p += __shfl_xor(p, 8);
            if (fr == 0) {
                int row = (wid * 4 + mt) * 16 + ((lane >> 4) << 2) + j;
                int e = e0 + row;
                if (e < E) out[e] = 1.f / (1.f + expf(-(0.5f * p + mb2v)));
            }
        }
}

// ---------------- launch ----------------

extern "C" void kernel_launch(void* const* d_in, const int* in_sizes, int n_in,
                              void* d_out, int out_size, void* d_ws, size_t ws_size,
                              hipStream_t stream) {
    const float* x     = (const float*)d_in[0];
    const int*   ei    = (const int*)d_in[1];
    const float* ew    = (const float*)d_in[2];
    const float* W0    = (const float*)d_in[3];
    const float* b0    = (const float*)d_in[4];
    const float* Wm    = (const float*)d_in[5];
    const float* bm    = (const float*)d_in[6];
    const float* Wl    = (const float*)d_in[7];
    const float* bl    = (const float*)d_in[8];
    const float* bn0_g = (const float*)d_in[9];
    const float* bn0_b = (const float*)d_in[10];
    const float* bnm_g = (const float*)d_in[11];
    const float* bnm_b = (const float*)d_in[12];
    const float* bno_g = (const float*)d_in[13];
    const float* bno_b = (const float*)d_in[14];
    const float* mW1   = (const float*)d_in[15];
    const float* mbn_g = (const float*)d_in[17];
    const float* mbn_b = (const float*)d_in[18];
    const float* mW2   = (const float*)d_in[19];
    const float* mb2   = (const float*)d_in[20];
    float* outp = (float*)d_out;

    char* ws = (char*)d_ws;
    unsigned long long* cw = (unsigned long long*)(ws + OFF_CW);
    int*    dout    = (int*)(ws + OFF_DOUT);
    float*  stats2  = (float*)(ws + OFF_STATS2);
    float*  sp8     = (float*)(ws + OFF_SP8);
    float*  MOM     = (float*)(ws + OFF_MOM);
    float*  st      = (float*)(ws + OFF_ST);
    float*  abw     = (float*)(ws + OFF_ABW);
    float*  w_in    = (float*)(ws + OFF_WIN);
    int*    offsets = (int*)(ws + OFF_OFFSETS);
    int*    srow    = (int*)(ws + OFF_SROW);
    float*  sew     = (float*)(ws + OFF_SEW);
    int*    rank    = (int*)(ws + OFF_RANK);
    ushort* Wt      = (ushort*)(ws + OFF_WT);
    ushort* Wp      = (ushort*)(ws + OFF_WP);
    __half* bufQ    = (__half*)(ws + OFF_BUFQ);
    __half* bufP    = (__half*)(ws + OFF_BUFP);
    // aliases inside bufQ (dead after 10th spmm; agg2 dead before 1st gemm)
    float*  agg2    = (float*)(ws + OFF_BUFQ + ALI_TMP16);
    float*  tmp16   = (float*)(ws + OFF_BUFQ + ALI_TMP16);
    float*  hraw    = (float*)(ws + OFF_BUFQ + ALI_HRAW);
    ushort* Z       = (ushort*)(ws + OFF_BUFQ + ALI_Z);
    float*  aggz    = (float*)(ws + OFF_BUFQ + ALI_AGGZ);

    const int N = NNODES, E = NEDGES;

    hipMemsetAsync(ws, 0, ZERO_END, stream);

    // CSR build (rank-based, no cursor atomics) + weight preconvert
    hist_kernel<<<1024, 256, 0, stream>>>(ei, ew, cw, dout, rank, E);
    wconv<<<640, 256, 0, stream>>>(Wm, Wt);
    wprep<<<1, 256, 0, stream>>>(mW1, Wp);
    scan_kernel<<<1, 1024, 0, stream>>>(cw, offsets, w_in, N);
    scatter_kernel<<<1024, 256, 0, stream>>>(ei, ew, offsets, rank, srow, sew, E);

    // ---- layer 0 ----
    colstats_wr<<<64, 256, 0, stream>>>(x, stats2 + 0 * 512, 2, N);
    bn_finalize<<<1, 256, 0, stream>>>(stats2 + 0 * 512, bn0_g, bn0_b, st, 2, N);
    spmm_small<<<(N + 127) / 128, 256, 0, stream>>>(x, srow, sew, offsets, agg2, 2, N, 0);
    layer0_fin<<<512, 256, 0, stream>>>(agg2, w_in, st, W0, b0, bufP, sp8 + 0 * 8192, N);

    // ---- 10 mid layers ----
    for (int i = 0; i < 10; i++) {
        gemm_mfma<<<dim3((N + 127) / 128, 2), 256, 0, stream>>>(
            bufP, Wt + i * 65536, bm + i * 256,
            sp8 + i * 8192, bnm_g + i * 256, bnm_b + i * 256, bufQ, N);
        spmm_f16w<<<2048, 256, 0, stream>>>(bufQ, srow, sew, offsets, bufP,
                                            sp8 + (i + 1) * 8192, N);
    }

    // ---- last GCN layer (256 -> 16) ----
    bn_finalize16<<<1, 256, 0, stream>>>(sp8 + 10 * 8192, bnm_g + 10 * 256,
                                         bnm_b + 10 * 256, st, N);
    gemm16<<<(N + 15) / 16, 256, 0, stream>>>(bufP, Wl, bl, st, tmp16, N);
    spmm_small<<<(N + 15) / 16, 256, 0, stream>>>(tmp16, srow, sew, offsets, hraw, 16, N, 1);

    // ---- final BN -> z (fp16) ----
    colstats_wr<<<64, 256, 0, stream>>>(hraw, stats2 + 1 * 512, 16, N);
    bn_finalize<<<1, 256, 0, stream>>>(stats2 + 1 * 512, bno_g, bno_b, st, 16, N);
    zprep<<<(N * 16 + 255) / 256, 256, 0, stream>>>(hraw, st, Z, N * 16);

    // ---- analytic edge-MLP BN stats ----
    aggz_spmm<<<(N + 15) / 16, 256, 0, stream>>>(Z, srow, offsets, aggz, N);
    zmom<<<256, 256, 0, stream>>>(Z, aggz, dout, cw, MOM, N);
    mlp_ab<<<1, 256, 0, stream>>>(MOM, mW1, mbn_g, mbn_b, mW2, abw, E);

    // ---- edge MLP output (MFMA) ----
    edge_mfma<<<(E + 255) / 256, 256, 0, stream>>>(Z, ei, Wp, abw, mb2, outp, E);
}